// Round 8
// baseline (224.127 us; speedup 1.0000x reference)
//
#include <hip/hip_runtime.h>
#include <math.h>

#define N_NODES 16384
#define D_MODEL 256
#define H_HEADS 4
#define C_CH 256
#define E_EDGES 65536
#define ETOT (E_EDGES + N_NODES)
#define HC 1024
#define ECACHE 64

typedef __bf16 bf16x8 __attribute__((ext_vector_type(8)));
typedef __bf16 bf16x4 __attribute__((ext_vector_type(4)));
typedef float f32x4 __attribute__((ext_vector_type(4)));

__device__ __forceinline__ __bf16 f2bf(float f) { return (__bf16)f; }
__device__ __forceinline__ float bf2f(__bf16 b) { return (float)b; }

// ---- small_t: t[v][d] = sum_c att_v[c] * Wg[h*256+c][d]  (atomic partials) ----
__global__ __launch_bounds__(256) void small_t(
    const float* __restrict__ Wg, const float* __restrict__ att_src,
    const float* __restrict__ att_dst, float* __restrict__ t)
{
    int v = blockIdx.x >> 3, sl = blockIdx.x & 7, h = v & 3;
    const float* att = ((v < 4) ? att_src : att_dst) + h * C_CH;
    int d = threadIdx.x;
    float acc = 0.f;
    #pragma unroll
    for (int j = 0; j < 32; ++j) {
        int c = sl * 32 + j;
        acc = fmaf(Wg[(size_t)(h * 256 + c) * 256 + d], att[c], acc);
    }
    atomicAdd(&t[v * 256 + d], acc);
}

// ---- small_u2: u2[v][d] = sum_k t[v][k]*W1[k][d];  c0[v] = dot(t[v], b1) ----
__global__ __launch_bounds__(256) void small_u2(
    const float* __restrict__ t, const float* __restrict__ W1,
    const float* __restrict__ b1, float* __restrict__ u2, float* __restrict__ c0)
{
    int v = blockIdx.x >> 3, sl = blockIdx.x & 7;
    int d = threadIdx.x;
    const float* tv = t + v * 256;
    float acc = 0.f;
    #pragma unroll
    for (int j = 0; j < 32; ++j) {
        int k = sl * 32 + j;
        acc = fmaf(tv[k], W1[(size_t)k * 256 + d], acc);
    }
    atomicAdd(&u2[v * 256 + d], acc);
    if (d < 32) {
        float p = tv[sl * 32 + d] * b1[sl * 32 + d];
        for (int s = 16; s; s >>= 1) p += __shfl_xor(p, s);
        if (d == 0) atomicAdd(&c0[v], p);
    }
}

// ---- compose_v: V[o][h*256+k] = sum_c W2[o][c] * Wg[h*256+c][k] ----
// 256 blocks: (o-group of 4) x h. Block reads Wg_h once (256 KB).
__global__ __launch_bounds__(256) void compose_v(
    const float* __restrict__ W2, const float* __restrict__ Wg,
    float* __restrict__ V)
{
    int og = (blockIdx.x & 63) * 4, h = blockIdx.x >> 6;
    int k = threadIdx.x;
    const float* w2r = W2 + (size_t)og * 256;
    const float* wgp = Wg + ((size_t)h * 256) * 256 + k;
    float a0 = 0.f, a1 = 0.f, a2 = 0.f, a3 = 0.f;
    #pragma unroll 4
    for (int c = 0; c < 256; ++c) {
        float wv = wgp[(size_t)c * 256];
        a0 = fmaf(w2r[c],       wv, a0);
        a1 = fmaf(w2r[256 + c], wv, a1);
        a2 = fmaf(w2r[512 + c], wv, a2);
        a3 = fmaf(w2r[768 + c], wv, a3);
    }
    size_t base = (size_t)og * 1024 + h * 256 + k;
    V[base]        = a0;
    V[base + 1024] = a1;
    V[base + 2048] = a2;
    V[base + 3072] = a3;
}

// ---- compose_wz: Wz[o][h*256+d] = sum_k V[o][h*256+k]*W1[k][d]  (bf16)
//      + bias_z[o] = 0.25*sum_hk V[o][hk]*b1[k] + dot(W2[o,:],bg) + b2[o] ----
__global__ __launch_bounds__(256) void compose_wz(
    const float* __restrict__ V, const float* __restrict__ W1,
    const float* __restrict__ b1, const float* __restrict__ W2,
    const float* __restrict__ bg, const float* __restrict__ b2,
    __bf16* __restrict__ Wz, float* __restrict__ bias_z)
{
    int og = (blockIdx.x & 63) * 4, h = blockIdx.x >> 6;
    int d = threadIdx.x;
    int lane = d & 63, wid = d >> 6;
    const float* vr = V + (size_t)og * 1024 + h * 256;
    float a0 = 0.f, a1 = 0.f, a2 = 0.f, a3 = 0.f;
    #pragma unroll 4
    for (int k = 0; k < 256; ++k) {
        float w1v = W1[(size_t)k * 256 + d];
        a0 = fmaf(vr[k],        w1v, a0);
        a1 = fmaf(vr[1024 + k], w1v, a1);
        a2 = fmaf(vr[2048 + k], w1v, a2);
        a3 = fmaf(vr[3072 + k], w1v, a3);
    }
    size_t base = (size_t)og * 1024 + h * 256 + d;
    Wz[base]        = f2bf(a0);
    Wz[base + 1024] = f2bf(a1);
    Wz[base + 2048] = f2bf(a2);
    Wz[base + 3072] = f2bf(a3);

    // bias partials: p_j = sum_k V[og+j][h*256+k]*b1[k]   (thread d = k)
    __shared__ float red[4][4];
    float b1v = b1[d];
    #pragma unroll
    for (int j = 0; j < 4; ++j) {
        float p = vr[(size_t)j * 1024 + d] * b1v;
        for (int s = 32; s; s >>= 1) p += __shfl_xor(p, s);
        if (lane == 0) red[j][wid] = p;
    }
    __syncthreads();
    if (d < 4) {
        float s = red[d][0] + red[d][1] + red[d][2] + red[d][3];
        atomicAdd(&bias_z[og + d], 0.25f * s);
    }
    if (h == 0) {
        __syncthreads();
        float bgv = bg[d];
        #pragma unroll
        for (int j = 0; j < 4; ++j) {
            float q = W2[(size_t)(og + j) * 256 + d] * bgv;
            for (int s = 32; s; s >>= 1) q += __shfl_xor(q, s);
            if (lane == 0) red[j][wid] = q;
        }
        __syncthreads();
        if (d < 4) {
            float s = red[d][0] + red[d][1] + red[d][2] + red[d][3];
            atomicAdd(&bias_z[og + d], s + b2[og + d]);
        }
    }
}

// ------- LayerNorm + fused attention logits: one row per wave -------
__global__ __launch_bounds__(256) void ln_logits(
    const float* __restrict__ in, const float* __restrict__ gamma,
    const float* __restrict__ beta, const float* __restrict__ u2,
    const float* __restrict__ c0, __bf16* __restrict__ out,
    float* __restrict__ a_src, float* __restrict__ a_dst)
{
    __shared__ float u2s[8][256];
    __shared__ float c0s[8];
    int tid = threadIdx.x;
    #pragma unroll
    for (int t = 0; t < 8; ++t) u2s[t][tid] = u2[t * 256 + tid];
    if (tid < 8) c0s[tid] = c0[tid];
    __syncthreads();

    int wave = tid >> 6, lane = tid & 63;
    int row = blockIdx.x * 4 + wave;
    float4 v = ((const float4*)(in + (size_t)row * D_MODEL))[lane];
    float s  = v.x + v.y + v.z + v.w;
    float sq = v.x*v.x + v.y*v.y + v.z*v.z + v.w*v.w;
    for (int off = 32; off; off >>= 1) {
        s  += __shfl_xor(s,  off);
        sq += __shfl_xor(sq, off);
    }
    float mean = s * (1.0f / D_MODEL);
    float var  = sq * (1.0f / D_MODEL) - mean * mean;
    float inv  = rsqrtf(var + 1e-6f);
    float4 g = ((const float4*)gamma)[lane];
    float4 b = ((const float4*)beta)[lane];
    float x0 = (v.x - mean) * inv * g.x + b.x;
    float x1 = (v.y - mean) * inv * g.y + b.y;
    float x2 = (v.z - mean) * inv * g.z + b.z;
    float x3 = (v.w - mean) * inv * g.w + b.w;
    bf16x4 o;
    o[0] = f2bf(x0); o[1] = f2bf(x1); o[2] = f2bf(x2); o[3] = f2bf(x3);
    *(bf16x4*)(out + (size_t)row * D_MODEL + lane * 4) = o;

    float p[8];
    #pragma unroll
    for (int k = 0; k < 8; ++k) {
        const float* up = &u2s[k][lane * 4];
        p[k] = x0 * up[0] + x1 * up[1] + x2 * up[2] + x3 * up[3];
    }
    #pragma unroll
    for (int k = 0; k < 8; ++k)
        for (int s2 = 32; s2; s2 >>= 1) p[k] += __shfl_xor(p[k], s2);
    if (lane == 0) {
        f32x4 ps = {p[0] + c0s[0], p[1] + c0s[1], p[2] + c0s[2], p[3] + c0s[3]};
        f32x4 pd = {p[4] + c0s[4], p[5] + c0s[5], p[6] + c0s[6], p[7] + c0s[7]};
        *(f32x4*)(a_src + row * H_HEADS) = ps;
        *(f32x4*)(a_dst + row * H_HEADS) = pd;
    }
}

// -------- bf16 MFMA GEMM: C[M,N] = A[M,K] * B[N,K]^T (+bias)(+resid) --------
#define BM 128
#define BN 128
#define BK 32
#define LDP 40   // LDS row stride (80B): max 2-way bank aliasing (free)

__global__ __launch_bounds__(256) void gemm_bf16_nt(
    const __bf16* __restrict__ A, const __bf16* __restrict__ B,
    int M, int N, int K,
    const float* __restrict__ bias, const float* __restrict__ resid,
    float* __restrict__ outf, __bf16* __restrict__ outb)
{
    __shared__ __bf16 As[BM * LDP];
    __shared__ __bf16 Bs[BN * LDP];
    int tid  = threadIdx.x;
    int lane = tid & 63;
    int w    = tid >> 6;
    int wm   = w >> 1, wn = w & 1;
    int quad = lane >> 4;
    int l16  = lane & 15;
    int m0 = blockIdx.y * BM;
    int n0 = blockIdx.x * BN;

    f32x4 acc[4][4] = {};

    for (int kb = 0; kb < K; kb += BK) {
        bf16x8 areg[2], breg[2];
        #pragma unroll
        for (int t = 0; t < 2; ++t) {
            int c = tid + t * 256;
            int r = c >> 2, p = c & 3;
            areg[t] = *(const bf16x8*)(A + (size_t)(m0 + r) * K + kb + p * 8);
            breg[t] = *(const bf16x8*)(B + (size_t)(n0 + r) * K + kb + p * 8);
        }
        __syncthreads();
        #pragma unroll
        for (int t = 0; t < 2; ++t) {
            int c = tid + t * 256;
            int r = c >> 2, p = c & 3;
            *(bf16x8*)(As + r * LDP + p * 8) = areg[t];
            *(bf16x8*)(Bs + r * LDP + p * 8) = breg[t];
        }
        __syncthreads();
        bf16x8 af[4], bfr[4];
        #pragma unroll
        for (int mt = 0; mt < 4; ++mt)
            af[mt] = *(const bf16x8*)(As + (wm * 64 + mt * 16 + l16) * LDP + quad * 8);
        #pragma unroll
        for (int nt = 0; nt < 4; ++nt)
            bfr[nt] = *(const bf16x8*)(Bs + (wn * 64 + nt * 16 + l16) * LDP + quad * 8);
        #pragma unroll
        for (int mt = 0; mt < 4; ++mt)
            #pragma unroll
            for (int nt = 0; nt < 4; ++nt)
                acc[mt][nt] = __builtin_amdgcn_mfma_f32_16x16x32_bf16(
                    af[mt], bfr[nt], acc[mt][nt], 0, 0, 0);
    }

    int rowb = m0 + wm * 64;
    int colb = n0 + wn * 64;
    #pragma unroll
    for (int nt = 0; nt < 4; ++nt) {
        int col = colb + nt * 16 + l16;
        float bv = bias ? bias[col] : 0.0f;
        #pragma unroll
        for (int mt = 0; mt < 4; ++mt) {
            int row = rowb + mt * 16 + quad * 4;
            #pragma unroll
            for (int r = 0; r < 4; ++r) {
                float v = acc[mt][nt][r] + bv;
                size_t off = (size_t)(row + r) * N + col;
                if (outf) {
                    if (resid) v += resid[off];
                    outf[off] = v;
                } else {
                    outb[off] = f2bf(v);
                }
            }
        }
    }
}

// ---------------- CSR build ----------------
__global__ void hist_kernel(const int* __restrict__ ei, int* __restrict__ deg)
{
    int e = blockIdx.x * blockDim.x + threadIdx.x;
    if (e >= ETOT) return;
    int dst = (e < E_EDGES) ? ei[E_EDGES + e] : (e - E_EDGES);
    atomicAdd(deg + dst, 1);
}

__global__ __launch_bounds__(1024) void scan_kernel(
    const int* __restrict__ deg, int* __restrict__ row_start)
{
    __shared__ int wsum[16];
    int tid = threadIdx.x;
    int lane = tid & 63, wid = tid >> 6;
    int base = tid * 16;
    int local[16];
    int run = 0;
    #pragma unroll
    for (int j = 0; j < 16; ++j) { local[j] = run; run += deg[base + j]; }
    int x = run;
    #pragma unroll
    for (int off = 1; off < 64; off <<= 1) {
        int y = __shfl_up(x, off);
        if (lane >= off) x += y;
    }
    if (lane == 63) wsum[wid] = x;
    __syncthreads();
    if (wid == 0) {
        int wv = (lane < 16) ? wsum[lane] : 0;
        int xx = wv;
        #pragma unroll
        for (int off = 1; off < 16; off <<= 1) {
            int y = __shfl_up(xx, off);
            if (lane >= off) xx += y;
        }
        if (lane < 16) wsum[lane] = xx - wv;
    }
    __syncthreads();
    int excl = wsum[wid] + (x - run);
    #pragma unroll
    for (int j = 0; j < 16; ++j) row_start[base + j] = excl + local[j];
    if (tid == 1023) row_start[N_NODES] = excl + run;
}

__global__ void scatter_kernel(const int* __restrict__ ei,
                               const int* __restrict__ row_start,
                               int* __restrict__ cnt, int* __restrict__ csr_src)
{
    int e = blockIdx.x * blockDim.x + threadIdx.x;
    if (e >= ETOT) return;
    int src, dst;
    if (e < E_EDGES) { src = ei[e]; dst = ei[E_EDGES + e]; }
    else             { src = dst = e - E_EDGES; }
    int pos = atomicAdd(cnt + dst, 1);
    csr_src[row_start[dst] + pos] = src;
}

// ---- fused softmax + aggregation in x_ln domain: one wave per node ----
// LDS-caches per-edge (src, leaky logits) from pass 1 (wave-local, no barrier).
__global__ __launch_bounds__(256) void gat_fused(
    const __bf16* __restrict__ x_ln, const float* __restrict__ a_src,
    const float* __restrict__ a_dst, const int* __restrict__ row_start,
    const int* __restrict__ csr_src, __bf16* __restrict__ agg)
{
    __shared__ int   sidx[4][ECACHE];
    __shared__ f32x4 slog[4][ECACHE];
    int wave = threadIdx.x >> 6, lane = threadIdx.x & 63;
    int i = blockIdx.x * 4 + wave;
    int rs = row_start[i], deg = row_start[i + 1] - rs;
    float4 ad = *(const float4*)(a_dst + i * H_HEADS);

    // pass 1: per-head max; cache src + logits in LDS
    float mx[4] = {-1e30f, -1e30f, -1e30f, -1e30f};
    for (int e = lane; e < deg; e += 64) {
        int s = csr_src[rs + e];
        float4 as = *(const float4*)(a_src + s * H_HEADS);
        float l0 = as.x + ad.x, l1 = as.y + ad.y, l2 = as.z + ad.z, l3 = as.w + ad.w;
        l0 = (l0 > 0.f) ? l0 : 0.2f * l0;
        l1 = (l1 > 0.f) ? l1 : 0.2f * l1;
        l2 = (l2 > 0.f) ? l2 : 0.2f * l2;
        l3 = (l3 > 0.f) ? l3 : 0.2f * l3;
        if (e < ECACHE) {
            sidx[wave][e] = s;
            f32x4 lv = {l0, l1, l2, l3};
            slog[wave][e] = lv;
        }
        mx[0] = fmaxf(mx[0], l0); mx[1] = fmaxf(mx[1], l1);
        mx[2] = fmaxf(mx[2], l2); mx[3] = fmaxf(mx[3], l3);
    }
    #pragma unroll
    for (int h = 0; h < 4; ++h)
        for (int off = 32; off; off >>= 1) mx[h] = fmaxf(mx[h], __shfl_xor(mx[h], off));

    // pass 2: exp + weighted accumulate + denom (lane owns 4 channels)
    float acc[4][4] = {};
    float sm0 = 0.f, sm1 = 0.f, sm2 = 0.f, sm3 = 0.f;
    int dcap = (deg < ECACHE) ? deg : ECACHE;
    for (int e = 0; e < dcap; ++e) {
        int s = sidx[wave][e];
        f32x4 lv = slog[wave][e];
        float w0 = __expf(lv[0] - mx[0]), w1 = __expf(lv[1] - mx[1]);
        float w2 = __expf(lv[2] - mx[2]), w3 = __expf(lv[3] - mx[3]);
        sm0 += w0; sm1 += w1; sm2 += w2; sm3 += w3;
        bf16x4 x = *(const bf16x4*)(x_ln + (size_t)s * D_MODEL + lane * 4);
        #pragma unroll
        for (int j = 0; j < 4; ++j) {
            float xv = bf2f(x[j]);
            acc[0][j] = fmaf(w0, xv, acc[0][j]);
            acc[1][j] = fmaf(w1, xv, acc[1][j]);
            acc[2][j] = fmaf(w2, xv, acc[2][j]);
            acc[3][j] = fmaf(w3, xv, acc[3][j]);
        }
    }
    for (int e = ECACHE; e < deg; ++e) {   // cold fallback (deg > 64: ~never)
        int s = csr_src[rs + e];
        float4 as = *(const float4*)(a_src + s * H_HEADS);
        float l0 = as.x + ad.x, l1 = as.y + ad.y, l2 = as.z + ad.z, l3 = as.w + ad.w;
        l0 = (l0 > 0.f) ? l0 : 0.2f * l0;
        l1 = (l1 > 0.f) ? l1 : 0.2f * l1;
        l2 = (l2 > 0.f) ? l2 : 0.2f * l2;
        l3 = (l3 > 0.f) ? l3 : 0.2f * l3;
        float w0 = __expf(l0 - mx[0]), w1 = __expf(l1 - mx[1]);
        float w2 = __expf(l2 - mx[2]), w3 = __expf(l3 - mx[3]);
        sm0 += w0; sm1 += w1; sm2 += w2; sm3 += w3;
        bf16x4 x = *(const bf16x4*)(x_ln + (size_t)s * D_MODEL + lane * 4);
        #pragma unroll
        for (int j = 0; j < 4; ++j) {
            float xv = bf2f(x[j]);
            acc[0][j] = fmaf(w0, xv, acc[0][j]);
            acc[1][j] = fmaf(w1, xv, acc[1][j]);
            acc[2][j] = fmaf(w2, xv, acc[2][j]);
            acc[3][j] = fmaf(w3, xv, acc[3][j]);
        }
    }
    float sc[4] = {0.25f / sm0, 0.25f / sm1, 0.25f / sm2, 0.25f / sm3};
    #pragma unroll
    for (int h = 0; h < 4; ++h) {
        bf16x4 o;
        #pragma unroll
        for (int j = 0; j < 4; ++j) o[j] = f2bf(acc[h][j] * sc[h]);
        *(bf16x4*)(agg + (size_t)i * HC + h * 256 + lane * 4) = o;
    }
}

extern "C" void kernel_launch(void* const* d_in, const int* in_sizes, int n_in,
                              void* d_out, int out_size, void* d_ws, size_t ws_size,
                              hipStream_t stream)
{
    const float* inp      = (const float*)d_in[0];
    const int*   ei       = (const int*)  d_in[1];
    const float* ln_gamma = (const float*)d_in[2];
    const float* ln_beta  = (const float*)d_in[3];
    const float* W1       = (const float*)d_in[4];
    const float* b1       = (const float*)d_in[5];
    const float* W_gat    = (const float*)d_in[6];
    const float* att_src  = (const float*)d_in[7];
    const float* att_dst  = (const float*)d_in[8];
    const float* bias_gat = (const float*)d_in[9];
    const float* W2       = (const float*)d_in[10];
    const float* b2       = (const float*)d_in[11];

    char* ws = (char*)d_ws;
    __bf16* x_ln_bf   = (__bf16*)(ws);                        //  8 MB
    __bf16* agg_bf    = (__bf16*)(ws + (8ull  << 20));        // 32 MB
    float*  V_f       = (float*)(ws + (40ull << 20));         //  1 MB
    __bf16* Wz_b      = (__bf16*)(ws + (41ull << 20));        // 512 KB
    float*  a_src_b   = (float*)(ws + (42ull << 20));         // 256 KB
    float*  a_dst_b   = a_src_b + (size_t)N_NODES * H_HEADS;  // 256 KB
    // ---- zero region start ----
    float*  t_vec     = a_dst_b + (size_t)N_NODES * H_HEADS;  //  8 KB
    float*  u2        = t_vec + 8 * 256;                      //  8 KB
    float*  c0        = u2 + 8 * 256;                         //  32 B
    float*  bias_z    = c0 + 8;                               //  1 KB
    int*    deg       = (int*)(bias_z + 256);                 // 64 KB
    int*    cnt       = deg + N_NODES;                        // 64 KB
    // ---- zero region end ----
    int*    row_st    = cnt + N_NODES;
    int*    csr_src   = row_st + N_NODES + 4;

    size_t zbytes = (8 * 256 + 8 * 256 + 8 + 256) * sizeof(float)
                  + 2 * N_NODES * sizeof(int);
    hipMemsetAsync(t_vec, 0, zbytes, stream);

    // prep: logit vectors, composite weights, CSR
    small_t<<<64, 256, 0, stream>>>(W_gat, att_src, att_dst, t_vec);
    small_u2<<<64, 256, 0, stream>>>(t_vec, W1, b1, u2, c0);
    compose_v<<<256, 256, 0, stream>>>(W2, W_gat, V_f);
    compose_wz<<<256, 256, 0, stream>>>(V_f, W1, b1, W2, bias_gat, b2, Wz_b, bias_z);
    hist_kernel<<<(ETOT + 255) / 256, 256, 0, stream>>>(ei, deg);
    scan_kernel<<<1, 1024, 0, stream>>>(deg, row_st);
    scatter_kernel<<<(ETOT + 255) / 256, 256, 0, stream>>>(ei, row_st, cnt, csr_src);

    // dense pipeline: LN+logits -> softmax+aggregate -> single composite GEMM
    ln_logits<<<N_NODES / 4, 256, 0, stream>>>(inp, ln_gamma, ln_beta, u2, c0,
                                               x_ln_bf, a_src_b, a_dst_b);
    gat_fused<<<N_NODES / 4, 256, 0, stream>>>(x_ln_bf, a_src_b, a_dst_b,
                                               row_st, csr_src, agg_bf);
    gemm_bf16_nt<<<dim3(C_CH / BN, N_NODES / BM), 256, 0, stream>>>(
        agg_bf, Wz_b, N_NODES, C_CH, HC, bias_z, inp, (float*)d_out, nullptr);
}

// Round 9
// 205.916 us; speedup vs baseline: 1.0884x; 1.0884x over previous
//
#include <hip/hip_runtime.h>
#include <math.h>

#define N_NODES 16384
#define D_MODEL 256
#define H_HEADS 4
#define C_CH 256
#define E_EDGES 65536
#define ETOT (E_EDGES + N_NODES)
#define HC 1024
#define ECACHE 64

typedef __bf16 bf16x8 __attribute__((ext_vector_type(8)));
typedef __bf16 bf16x4 __attribute__((ext_vector_type(4)));
typedef float f32x4 __attribute__((ext_vector_type(4)));

__device__ __forceinline__ __bf16 f2bf(float f) { return (__bf16)f; }
__device__ __forceinline__ float bf2f(__bf16 b) { return (float)b; }

// ---- small_t: t[v][d] = sum_c att_v[c] * Wg[h*256+c][d]  (atomic partials) ----
__global__ __launch_bounds__(256) void small_t(
    const float* __restrict__ Wg, const float* __restrict__ att_src,
    const float* __restrict__ att_dst, float* __restrict__ t)
{
    int v = blockIdx.x >> 3, sl = blockIdx.x & 7, h = v & 3;
    const float* att = ((v < 4) ? att_src : att_dst) + h * C_CH;
    int d = threadIdx.x;
    float acc = 0.f;
    #pragma unroll
    for (int j = 0; j < 32; ++j) {
        int c = sl * 32 + j;
        acc = fmaf(Wg[(size_t)(h * 256 + c) * 256 + d], att[c], acc);
    }
    atomicAdd(&t[v * 256 + d], acc);
}

// ---- small_u2: u2[v][d] = sum_k t[v][k]*W1[k][d];  c0[v] = dot(t[v], b1) ----
__global__ __launch_bounds__(256) void small_u2(
    const float* __restrict__ t, const float* __restrict__ W1,
    const float* __restrict__ b1, float* __restrict__ u2, float* __restrict__ c0)
{
    int v = blockIdx.x >> 3, sl = blockIdx.x & 7;
    int d = threadIdx.x;
    const float* tv = t + v * 256;
    float acc = 0.f;
    #pragma unroll
    for (int j = 0; j < 32; ++j) {
        int k = sl * 32 + j;
        acc = fmaf(tv[k], W1[(size_t)k * 256 + d], acc);
    }
    atomicAdd(&u2[v * 256 + d], acc);
    if (d < 32) {
        float p = tv[sl * 32 + d] * b1[sl * 32 + d];
        for (int s = 16; s; s >>= 1) p += __shfl_xor(p, s);
        if (d == 0) atomicAdd(&c0[v], p);
    }
}

// ---- compose_v: V[o][h*256+k] = sum_c W2[o][c] * Wg[h*256+c][k] ----
__global__ __launch_bounds__(256) void compose_v(
    const float* __restrict__ W2, const float* __restrict__ Wg,
    float* __restrict__ V)
{
    int og = (blockIdx.x & 63) * 4, h = blockIdx.x >> 6;
    int k = threadIdx.x;
    const float* w2r = W2 + (size_t)og * 256;
    const float* wgp = Wg + ((size_t)h * 256) * 256 + k;
    float a0 = 0.f, a1 = 0.f, a2 = 0.f, a3 = 0.f;
    #pragma unroll 4
    for (int c = 0; c < 256; ++c) {
        float wv = wgp[(size_t)c * 256];
        a0 = fmaf(w2r[c],       wv, a0);
        a1 = fmaf(w2r[256 + c], wv, a1);
        a2 = fmaf(w2r[512 + c], wv, a2);
        a3 = fmaf(w2r[768 + c], wv, a3);
    }
    size_t base = (size_t)og * 1024 + h * 256 + k;
    V[base]        = a0;
    V[base + 1024] = a1;
    V[base + 2048] = a2;
    V[base + 3072] = a3;
}

// ---- compose_wz: Wz[o][h*256+d] = sum_k V[o][h*256+k]*W1[k][d]  (bf16)
//      + bias_z[o] = 0.25*sum_hk V[o][hk]*b1[k] + dot(W2[o,:],bg) + b2[o] ----
__global__ __launch_bounds__(256) void compose_wz(
    const float* __restrict__ V, const float* __restrict__ W1,
    const float* __restrict__ b1, const float* __restrict__ W2,
    const float* __restrict__ bg, const float* __restrict__ b2,
    __bf16* __restrict__ Wz, float* __restrict__ bias_z)
{
    int og = (blockIdx.x & 63) * 4, h = blockIdx.x >> 6;
    int d = threadIdx.x;
    int lane = d & 63, wid = d >> 6;
    const float* vr = V + (size_t)og * 1024 + h * 256;
    float a0 = 0.f, a1 = 0.f, a2 = 0.f, a3 = 0.f;
    #pragma unroll 4
    for (int k = 0; k < 256; ++k) {
        float w1v = W1[(size_t)k * 256 + d];
        a0 = fmaf(vr[k],        w1v, a0);
        a1 = fmaf(vr[1024 + k], w1v, a1);
        a2 = fmaf(vr[2048 + k], w1v, a2);
        a3 = fmaf(vr[3072 + k], w1v, a3);
    }
    size_t base = (size_t)og * 1024 + h * 256 + d;
    Wz[base]        = f2bf(a0);
    Wz[base + 1024] = f2bf(a1);
    Wz[base + 2048] = f2bf(a2);
    Wz[base + 3072] = f2bf(a3);

    __shared__ float red[4][4];
    float b1v = b1[d];
    #pragma unroll
    for (int j = 0; j < 4; ++j) {
        float p = vr[(size_t)j * 1024 + d] * b1v;
        for (int s = 32; s; s >>= 1) p += __shfl_xor(p, s);
        if (lane == 0) red[j][wid] = p;
    }
    __syncthreads();
    if (d < 4) {
        float s = red[d][0] + red[d][1] + red[d][2] + red[d][3];
        atomicAdd(&bias_z[og + d], 0.25f * s);
    }
    if (h == 0) {
        __syncthreads();
        float bgv = bg[d];
        #pragma unroll
        for (int j = 0; j < 4; ++j) {
            float q = W2[(size_t)(og + j) * 256 + d] * bgv;
            for (int s = 32; s; s >>= 1) q += __shfl_xor(q, s);
            if (lane == 0) red[j][wid] = q;
        }
        __syncthreads();
        if (d < 4) {
            float s = red[d][0] + red[d][1] + red[d][2] + red[d][3];
            atomicAdd(&bias_z[og + d], s + b2[og + d]);
        }
    }
}

// ------- LayerNorm + fused attention logits: one row per wave -------
__global__ __launch_bounds__(256) void ln_logits(
    const float* __restrict__ in, const float* __restrict__ gamma,
    const float* __restrict__ beta, const float* __restrict__ u2,
    const float* __restrict__ c0, __bf16* __restrict__ out,
    float* __restrict__ a_src, float* __restrict__ a_dst)
{
    __shared__ float u2s[8][256];
    __shared__ float c0s[8];
    int tid = threadIdx.x;
    #pragma unroll
    for (int t = 0; t < 8; ++t) u2s[t][tid] = u2[t * 256 + tid];
    if (tid < 8) c0s[tid] = c0[tid];
    __syncthreads();

    int wave = tid >> 6, lane = tid & 63;
    int row = blockIdx.x * 4 + wave;
    float4 v = ((const float4*)(in + (size_t)row * D_MODEL))[lane];
    float s  = v.x + v.y + v.z + v.w;
    float sq = v.x*v.x + v.y*v.y + v.z*v.z + v.w*v.w;
    for (int off = 32; off; off >>= 1) {
        s  += __shfl_xor(s,  off);
        sq += __shfl_xor(sq, off);
    }
    float mean = s * (1.0f / D_MODEL);
    float var  = sq * (1.0f / D_MODEL) - mean * mean;
    float inv  = rsqrtf(var + 1e-6f);
    float4 g = ((const float4*)gamma)[lane];
    float4 b = ((const float4*)beta)[lane];
    float x0 = (v.x - mean) * inv * g.x + b.x;
    float x1 = (v.y - mean) * inv * g.y + b.y;
    float x2 = (v.z - mean) * inv * g.z + b.z;
    float x3 = (v.w - mean) * inv * g.w + b.w;
    bf16x4 o;
    o[0] = f2bf(x0); o[1] = f2bf(x1); o[2] = f2bf(x2); o[3] = f2bf(x3);
    *(bf16x4*)(out + (size_t)row * D_MODEL + lane * 4) = o;

    float p[8];
    #pragma unroll
    for (int k = 0; k < 8; ++k) {
        const float* up = &u2s[k][lane * 4];
        p[k] = x0 * up[0] + x1 * up[1] + x2 * up[2] + x3 * up[3];
    }
    #pragma unroll
    for (int k = 0; k < 8; ++k)
        for (int s2 = 32; s2; s2 >>= 1) p[k] += __shfl_xor(p[k], s2);
    if (lane == 0) {
        f32x4 ps = {p[0] + c0s[0], p[1] + c0s[1], p[2] + c0s[2], p[3] + c0s[3]};
        f32x4 pd = {p[4] + c0s[4], p[5] + c0s[5], p[6] + c0s[6], p[7] + c0s[7]};
        *(f32x4*)(a_src + row * H_HEADS) = ps;
        *(f32x4*)(a_dst + row * H_HEADS) = pd;
    }
}

// -------- skinny bf16 GEMM: out[M,256] = A[M,K]·B[256,K]^T + bias + resid --------
// 64x64 block tile -> grid (4, M/64) = 1024 blocks (4/CU), 2x2 waves of 32x32.
#define LDP 40   // LDS row stride (80B): max 2-way bank aliasing (free)

__global__ __launch_bounds__(256) void gemm_skinny(
    const __bf16* __restrict__ A, const __bf16* __restrict__ B,
    const float* __restrict__ bias, const float* __restrict__ resid,
    float* __restrict__ outf, int K)
{
    __shared__ __bf16 As[64 * LDP];
    __shared__ __bf16 Bs[64 * LDP];
    int tid  = threadIdx.x;
    int lane = tid & 63;
    int w    = tid >> 6;
    int wm   = w >> 1, wn = w & 1;
    int quad = lane >> 4;
    int l16  = lane & 15;
    int m0 = blockIdx.y * 64;
    int n0 = blockIdx.x * 64;
    int lr = tid >> 2, lp = (tid & 3) * 8;   // staging: row 0..63, k-slice 0..31

    f32x4 acc[2][2] = {};

    for (int kb = 0; kb < K; kb += 32) {
        bf16x8 areg = *(const bf16x8*)(A + (size_t)(m0 + lr) * K + kb + lp);
        bf16x8 breg = *(const bf16x8*)(B + (size_t)(n0 + lr) * K + kb + lp);
        __syncthreads();
        *(bf16x8*)(As + lr * LDP + lp) = areg;
        *(bf16x8*)(Bs + lr * LDP + lp) = breg;
        __syncthreads();
        bf16x8 af[2], bfr[2];
        #pragma unroll
        for (int mt = 0; mt < 2; ++mt)
            af[mt] = *(const bf16x8*)(As + (wm * 32 + mt * 16 + l16) * LDP + quad * 8);
        #pragma unroll
        for (int nt = 0; nt < 2; ++nt)
            bfr[nt] = *(const bf16x8*)(Bs + (wn * 32 + nt * 16 + l16) * LDP + quad * 8);
        #pragma unroll
        for (int mt = 0; mt < 2; ++mt)
            #pragma unroll
            for (int nt = 0; nt < 2; ++nt)
                acc[mt][nt] = __builtin_amdgcn_mfma_f32_16x16x32_bf16(
                    af[mt], bfr[nt], acc[mt][nt], 0, 0, 0);
    }

    int rowb = m0 + wm * 32;
    int colb = n0 + wn * 32;
    #pragma unroll
    for (int nt = 0; nt < 2; ++nt) {
        int col = colb + nt * 16 + l16;
        float bv = bias[col];
        #pragma unroll
        for (int mt = 0; mt < 2; ++mt) {
            int row = rowb + mt * 16 + quad * 4;
            #pragma unroll
            for (int r = 0; r < 4; ++r) {
                size_t off = (size_t)(row + r) * C_CH + col;
                outf[off] = acc[mt][nt][r] + bv + resid[off];
            }
        }
    }
}

// ---------------- CSR build ----------------
__global__ void hist_kernel(const int* __restrict__ ei, int* __restrict__ deg)
{
    int e = blockIdx.x * blockDim.x + threadIdx.x;
    if (e >= ETOT) return;
    int dst = (e < E_EDGES) ? ei[E_EDGES + e] : (e - E_EDGES);
    atomicAdd(deg + dst, 1);
}

__global__ __launch_bounds__(1024) void scan_kernel(
    const int* __restrict__ deg, int* __restrict__ row_start)
{
    __shared__ int wsum[16];
    int tid = threadIdx.x;
    int lane = tid & 63, wid = tid >> 6;
    int base = tid * 16;
    int local[16];
    int run = 0;
    #pragma unroll
    for (int j = 0; j < 16; ++j) { local[j] = run; run += deg[base + j]; }
    int x = run;
    #pragma unroll
    for (int off = 1; off < 64; off <<= 1) {
        int y = __shfl_up(x, off);
        if (lane >= off) x += y;
    }
    if (lane == 63) wsum[wid] = x;
    __syncthreads();
    if (wid == 0) {
        int wv = (lane < 16) ? wsum[lane] : 0;
        int xx = wv;
        #pragma unroll
        for (int off = 1; off < 16; off <<= 1) {
            int y = __shfl_up(xx, off);
            if (lane >= off) xx += y;
        }
        if (lane < 16) wsum[lane] = xx - wv;
    }
    __syncthreads();
    int excl = wsum[wid] + (x - run);
    #pragma unroll
    for (int j = 0; j < 16; ++j) row_start[base + j] = excl + local[j];
    if (tid == 1023) row_start[N_NODES] = excl + run;
}

__global__ void scatter_kernel(const int* __restrict__ ei,
                               const int* __restrict__ row_start,
                               int* __restrict__ cnt, int* __restrict__ csr_src)
{
    int e = blockIdx.x * blockDim.x + threadIdx.x;
    if (e >= ETOT) return;
    int src, dst;
    if (e < E_EDGES) { src = ei[e]; dst = ei[E_EDGES + e]; }
    else             { src = dst = e - E_EDGES; }
    int pos = atomicAdd(cnt + dst, 1);
    csr_src[row_start[dst] + pos] = src;
}

// ---- fused softmax + aggregation in x_ln domain: one wave per node ----
__global__ __launch_bounds__(256) void gat_fused(
    const __bf16* __restrict__ x_ln, const float* __restrict__ a_src,
    const float* __restrict__ a_dst, const int* __restrict__ row_start,
    const int* __restrict__ csr_src, __bf16* __restrict__ agg)
{
    __shared__ int   sidx[4][ECACHE];
    __shared__ f32x4 slog[4][ECACHE];
    int wave = threadIdx.x >> 6, lane = threadIdx.x & 63;
    int i = blockIdx.x * 4 + wave;
    int rs = row_start[i], deg = row_start[i + 1] - rs;
    float4 ad = *(const float4*)(a_dst + i * H_HEADS);

    float mx[4] = {-1e30f, -1e30f, -1e30f, -1e30f};
    for (int e = lane; e < deg; e += 64) {
        int s = csr_src[rs + e];
        float4 as = *(const float4*)(a_src + s * H_HEADS);
        float l0 = as.x + ad.x, l1 = as.y + ad.y, l2 = as.z + ad.z, l3 = as.w + ad.w;
        l0 = (l0 > 0.f) ? l0 : 0.2f * l0;
        l1 = (l1 > 0.f) ? l1 : 0.2f * l1;
        l2 = (l2 > 0.f) ? l2 : 0.2f * l2;
        l3 = (l3 > 0.f) ? l3 : 0.2f * l3;
        if (e < ECACHE) {
            sidx[wave][e] = s;
            f32x4 lv = {l0, l1, l2, l3};
            slog[wave][e] = lv;
        }
        mx[0] = fmaxf(mx[0], l0); mx[1] = fmaxf(mx[1], l1);
        mx[2] = fmaxf(mx[2], l2); mx[3] = fmaxf(mx[3], l3);
    }
    #pragma unroll
    for (int h = 0; h < 4; ++h)
        for (int off = 32; off; off >>= 1) mx[h] = fmaxf(mx[h], __shfl_xor(mx[h], off));

    float acc[4][4] = {};
    float sm0 = 0.f, sm1 = 0.f, sm2 = 0.f, sm3 = 0.f;
    int dcap = (deg < ECACHE) ? deg : ECACHE;
    for (int e = 0; e < dcap; ++e) {
        int s = sidx[wave][e];
        f32x4 lv = slog[wave][e];
        float w0 = __expf(lv[0] - mx[0]), w1 = __expf(lv[1] - mx[1]);
        float w2 = __expf(lv[2] - mx[2]), w3 = __expf(lv[3] - mx[3]);
        sm0 += w0; sm1 += w1; sm2 += w2; sm3 += w3;
        bf16x4 x = *(const bf16x4*)(x_ln + (size_t)s * D_MODEL + lane * 4);
        #pragma unroll
        for (int j = 0; j < 4; ++j) {
            float xv = bf2f(x[j]);
            acc[0][j] = fmaf(w0, xv, acc[0][j]);
            acc[1][j] = fmaf(w1, xv, acc[1][j]);
            acc[2][j] = fmaf(w2, xv, acc[2][j]);
            acc[3][j] = fmaf(w3, xv, acc[3][j]);
        }
    }
    for (int e = ECACHE; e < deg; ++e) {
        int s = csr_src[rs + e];
        float4 as = *(const float4*)(a_src + s * H_HEADS);
        float l0 = as.x + ad.x, l1 = as.y + ad.y, l2 = as.z + ad.z, l3 = as.w + ad.w;
        l0 = (l0 > 0.f) ? l0 : 0.2f * l0;
        l1 = (l1 > 0.f) ? l1 : 0.2f * l1;
        l2 = (l2 > 0.f) ? l2 : 0.2f * l2;
        l3 = (l3 > 0.f) ? l3 : 0.2f * l3;
        float w0 = __expf(l0 - mx[0]), w1 = __expf(l1 - mx[1]);
        float w2 = __expf(l2 - mx[2]), w3 = __expf(l3 - mx[3]);
        sm0 += w0; sm1 += w1; sm2 += w2; sm3 += w3;
        bf16x4 x = *(const bf16x4*)(x_ln + (size_t)s * D_MODEL + lane * 4);
        #pragma unroll
        for (int j = 0; j < 4; ++j) {
            float xv = bf2f(x[j]);
            acc[0][j] = fmaf(w0, xv, acc[0][j]);
            acc[1][j] = fmaf(w1, xv, acc[1][j]);
            acc[2][j] = fmaf(w2, xv, acc[2][j]);
            acc[3][j] = fmaf(w3, xv, acc[3][j]);
        }
    }
    float sc[4] = {0.25f / sm0, 0.25f / sm1, 0.25f / sm2, 0.25f / sm3};
    #pragma unroll
    for (int h = 0; h < 4; ++h) {
        bf16x4 o;
        #pragma unroll
        for (int j = 0; j < 4; ++j) o[j] = f2bf(acc[h][j] * sc[h]);
        *(bf16x4*)(agg + (size_t)i * HC + h * 256 + lane * 4) = o;
    }
}

extern "C" void kernel_launch(void* const* d_in, const int* in_sizes, int n_in,
                              void* d_out, int out_size, void* d_ws, size_t ws_size,
                              hipStream_t stream)
{
    const float* inp      = (const float*)d_in[0];
    const int*   ei       = (const int*)  d_in[1];
    const float* ln_gamma = (const float*)d_in[2];
    const float* ln_beta  = (const float*)d_in[3];
    const float* W1       = (const float*)d_in[4];
    const float* b1       = (const float*)d_in[5];
    const float* W_gat    = (const float*)d_in[6];
    const float* att_src  = (const float*)d_in[7];
    const float* att_dst  = (const float*)d_in[8];
    const float* bias_gat = (const float*)d_in[9];
    const float* W2       = (const float*)d_in[10];
    const float* b2       = (const float*)d_in[11];

    char* ws = (char*)d_ws;
    __bf16* x_ln_bf   = (__bf16*)(ws);                        //  8 MB
    __bf16* agg_bf    = (__bf16*)(ws + (8ull  << 20));        // 32 MB
    float*  V_f       = (float*)(ws + (40ull << 20));         //  1 MB
    __bf16* Wz_b      = (__bf16*)(ws + (41ull << 20));        // 512 KB
    float*  a_src_b   = (float*)(ws + (42ull << 20));         // 256 KB
    float*  a_dst_b   = a_src_b + (size_t)N_NODES * H_HEADS;  // 256 KB
    // ---- zero region start ----
    float*  t_vec     = a_dst_b + (size_t)N_NODES * H_HEADS;  //  8 KB
    float*  u2        = t_vec + 8 * 256;                      //  8 KB
    float*  c0        = u2 + 8 * 256;                         //  32 B
    float*  bias_z    = c0 + 8;                               //  1 KB
    int*    deg       = (int*)(bias_z + 256);                 // 64 KB
    int*    cnt       = deg + N_NODES;                        // 64 KB
    // ---- zero region end ----
    int*    row_st    = cnt + N_NODES;
    int*    csr_src   = row_st + N_NODES + 4;

    size_t zbytes = (8 * 256 + 8 * 256 + 8 + 256) * sizeof(float)
                  + 2 * N_NODES * sizeof(int);
    hipMemsetAsync(t_vec, 0, zbytes, stream);

    // prep: logit vectors, composite weights, CSR
    small_t<<<64, 256, 0, stream>>>(W_gat, att_src, att_dst, t_vec);
    small_u2<<<64, 256, 0, stream>>>(t_vec, W1, b1, u2, c0);
    compose_v<<<256, 256, 0, stream>>>(W2, W_gat, V_f);
    compose_wz<<<256, 256, 0, stream>>>(V_f, W1, b1, W2, bias_gat, b2, Wz_b, bias_z);
    hist_kernel<<<(ETOT + 255) / 256, 256, 0, stream>>>(ei, deg);
    scan_kernel<<<1, 1024, 0, stream>>>(deg, row_st);
    scatter_kernel<<<(ETOT + 255) / 256, 256, 0, stream>>>(ei, row_st, cnt, csr_src);

    // dense pipeline: LN+logits -> softmax+aggregate -> single composite GEMM
    ln_logits<<<N_NODES / 4, 256, 0, stream>>>(inp, ln_gamma, ln_beta, u2, c0,
                                               x_ln_bf, a_src_b, a_dst_b);
    gat_fused<<<N_NODES / 4, 256, 0, stream>>>(x_ln_bf, a_src_b, a_dst_b,
                                               row_st, csr_src, agg_bf);
    gemm_skinny<<<dim3(C_CH / 64, N_NODES / 64), 256, 0, stream>>>(
        agg_bf, Wz_b, bias_z, inp, (float*)d_out, HC);
}

// Round 10
// 198.975 us; speedup vs baseline: 1.1264x; 1.0349x over previous
//
#include <hip/hip_runtime.h>
#include <math.h>

#define N_NODES 16384
#define D_MODEL 256
#define H_HEADS 4
#define C_CH 256
#define E_EDGES 65536
#define ETOT (E_EDGES + N_NODES)
#define HC 1024

typedef __bf16 bf16x8 __attribute__((ext_vector_type(8)));
typedef __bf16 bf16x4 __attribute__((ext_vector_type(4)));
typedef float f32x4 __attribute__((ext_vector_type(4)));

__device__ __forceinline__ __bf16 f2bf(float f) { return (__bf16)f; }
__device__ __forceinline__ float bf2f(__bf16 b) { return (float)b; }

// ==== prep1: blocks 0..63 t-partials | 64..319 compose_v | 320..639 hist ====
// t[v][d]    = sum_c att_v[c] * Wg[h*256+c][d]      (atomic into pre-zeroed t)
// V[o][hk]   = sum_c W2[o][c] * Wg[h*256+c][k]
// deg[dst]  += 1 per edge (incl. self loops)
__global__ __launch_bounds__(256) void prep1(
    const float* __restrict__ Wg, const float* __restrict__ att_src,
    const float* __restrict__ att_dst, const float* __restrict__ W2,
    const int* __restrict__ ei, float* __restrict__ t,
    float* __restrict__ V, int* __restrict__ deg)
{
    int b = blockIdx.x;
    int tid = threadIdx.x;
    if (b < 64) {
        int v = b >> 3, sl = b & 7, h = v & 3;
        const float* att = ((v < 4) ? att_src : att_dst) + h * C_CH;
        float acc = 0.f;
        #pragma unroll
        for (int j = 0; j < 32; ++j) {
            int c = sl * 32 + j;
            acc = fmaf(Wg[(size_t)(h * 256 + c) * 256 + tid], att[c], acc);
        }
        atomicAdd(&t[v * 256 + tid], acc);
    } else if (b < 320) {
        int bb = b - 64;
        int og = (bb & 63) * 4, h = bb >> 6;
        const float* w2r = W2 + (size_t)og * 256;
        const float* wgp = Wg + ((size_t)h * 256) * 256 + tid;
        float a0 = 0.f, a1 = 0.f, a2 = 0.f, a3 = 0.f;
        #pragma unroll 4
        for (int c = 0; c < 256; ++c) {
            float wv = wgp[(size_t)c * 256];
            a0 = fmaf(w2r[c],       wv, a0);
            a1 = fmaf(w2r[256 + c], wv, a1);
            a2 = fmaf(w2r[512 + c], wv, a2);
            a3 = fmaf(w2r[768 + c], wv, a3);
        }
        size_t base = (size_t)og * 1024 + h * 256 + tid;
        V[base]        = a0;
        V[base + 1024] = a1;
        V[base + 2048] = a2;
        V[base + 3072] = a3;
    } else {
        int e = (b - 320) * 256 + tid;
        int dst = (e < E_EDGES) ? ei[E_EDGES + e] : (e - E_EDGES);
        atomicAdd(deg + dst, 1);
    }
}

// ==== prep2: blocks 0..63 u2/c0 partials | 64..319 compose_wz + bias_z ====
__global__ __launch_bounds__(256) void prep2(
    const float* __restrict__ t, const float* __restrict__ W1,
    const float* __restrict__ b1, const float* __restrict__ V,
    const float* __restrict__ W2, const float* __restrict__ bg,
    const float* __restrict__ b2, float* __restrict__ u2,
    float* __restrict__ c0, __bf16* __restrict__ Wz,
    float* __restrict__ bias_z)
{
    int b = blockIdx.x;
    int d = threadIdx.x;
    if (b < 64) {
        int v = b >> 3, sl = b & 7;
        const float* tv = t + v * 256;
        float acc = 0.f;
        #pragma unroll
        for (int j = 0; j < 32; ++j) {
            int k = sl * 32 + j;
            acc = fmaf(tv[k], W1[(size_t)k * 256 + d], acc);
        }
        atomicAdd(&u2[v * 256 + d], acc);
        if (d < 32) {
            float p = tv[sl * 32 + d] * b1[sl * 32 + d];
            for (int s = 16; s; s >>= 1) p += __shfl_xor(p, s);
            if (d == 0) atomicAdd(&c0[v], p);
        }
        return;
    }
    int bb = b - 64;
    int og = (bb & 63) * 4, h = bb >> 6;
    int lane = d & 63, wid = d >> 6;
    const float* vr = V + (size_t)og * 1024 + h * 256;
    float a0 = 0.f, a1 = 0.f, a2 = 0.f, a3 = 0.f;
    #pragma unroll 4
    for (int k = 0; k < 256; ++k) {
        float w1v = W1[(size_t)k * 256 + d];
        a0 = fmaf(vr[k],        w1v, a0);
        a1 = fmaf(vr[1024 + k], w1v, a1);
        a2 = fmaf(vr[2048 + k], w1v, a2);
        a3 = fmaf(vr[3072 + k], w1v, a3);
    }
    size_t base = (size_t)og * 1024 + h * 256 + d;
    Wz[base]        = f2bf(a0);
    Wz[base + 1024] = f2bf(a1);
    Wz[base + 2048] = f2bf(a2);
    Wz[base + 3072] = f2bf(a3);

    __shared__ float red[4][4];
    float b1v = b1[d];
    #pragma unroll
    for (int j = 0; j < 4; ++j) {
        float p = vr[(size_t)j * 1024 + d] * b1v;
        for (int s = 32; s; s >>= 1) p += __shfl_xor(p, s);
        if (lane == 0) red[j][wid] = p;
    }
    __syncthreads();
    if (d < 4) {
        float s = red[d][0] + red[d][1] + red[d][2] + red[d][3];
        atomicAdd(&bias_z[og + d], 0.25f * s);
    }
    if (h == 0) {
        __syncthreads();
        float bgv = bg[d];
        #pragma unroll
        for (int j = 0; j < 4; ++j) {
            float q = W2[(size_t)(og + j) * 256 + d] * bgv;
            for (int s = 32; s; s >>= 1) q += __shfl_xor(q, s);
            if (lane == 0) red[j][wid] = q;
        }
        __syncthreads();
        if (d < 4) {
            float s = red[d][0] + red[d][1] + red[d][2] + red[d][3];
            atomicAdd(&bias_z[og + d], s + b2[og + d]);
        }
    }
}

// ------- LayerNorm + fused attention logits: one row per wave -------
__global__ __launch_bounds__(256) void ln_logits(
    const float* __restrict__ in, const float* __restrict__ gamma,
    const float* __restrict__ beta, const float* __restrict__ u2,
    const float* __restrict__ c0, __bf16* __restrict__ out,
    float* __restrict__ a_src, float* __restrict__ a_dst)
{
    __shared__ float u2s[8][256];
    __shared__ float c0s[8];
    int tid = threadIdx.x;
    #pragma unroll
    for (int t = 0; t < 8; ++t) u2s[t][tid] = u2[t * 256 + tid];
    if (tid < 8) c0s[tid] = c0[tid];
    __syncthreads();

    int wave = tid >> 6, lane = tid & 63;
    int row = blockIdx.x * 4 + wave;
    float4 v = ((const float4*)(in + (size_t)row * D_MODEL))[lane];
    float s  = v.x + v.y + v.z + v.w;
    float sq = v.x*v.x + v.y*v.y + v.z*v.z + v.w*v.w;
    for (int off = 32; off; off >>= 1) {
        s  += __shfl_xor(s,  off);
        sq += __shfl_xor(sq, off);
    }
    float mean = s * (1.0f / D_MODEL);
    float var  = sq * (1.0f / D_MODEL) - mean * mean;
    float inv  = rsqrtf(var + 1e-6f);
    float4 g = ((const float4*)gamma)[lane];
    float4 b = ((const float4*)beta)[lane];
    float x0 = (v.x - mean) * inv * g.x + b.x;
    float x1 = (v.y - mean) * inv * g.y + b.y;
    float x2 = (v.z - mean) * inv * g.z + b.z;
    float x3 = (v.w - mean) * inv * g.w + b.w;
    bf16x4 o;
    o[0] = f2bf(x0); o[1] = f2bf(x1); o[2] = f2bf(x2); o[3] = f2bf(x3);
    *(bf16x4*)(out + (size_t)row * D_MODEL + lane * 4) = o;

    float p[8];
    #pragma unroll
    for (int k = 0; k < 8; ++k) {
        const float* up = &u2s[k][lane * 4];
        p[k] = x0 * up[0] + x1 * up[1] + x2 * up[2] + x3 * up[3];
    }
    #pragma unroll
    for (int k = 0; k < 8; ++k)
        for (int s2 = 32; s2; s2 >>= 1) p[k] += __shfl_xor(p[k], s2);
    if (lane == 0) {
        f32x4 ps = {p[0] + c0s[0], p[1] + c0s[1], p[2] + c0s[2], p[3] + c0s[3]};
        f32x4 pd = {p[4] + c0s[4], p[5] + c0s[5], p[6] + c0s[6], p[7] + c0s[7]};
        *(f32x4*)(a_src + row * H_HEADS) = ps;
        *(f32x4*)(a_dst + row * H_HEADS) = pd;
    }
}

// -------- skinny bf16 GEMM: out[M,256] = A[M,K]·B[256,K]^T + bias + resid --------
#define LDP 40   // LDS row stride (80B): max 2-way bank aliasing (free)

__global__ __launch_bounds__(256) void gemm_skinny(
    const __bf16* __restrict__ A, const __bf16* __restrict__ B,
    const float* __restrict__ bias, const float* __restrict__ resid,
    float* __restrict__ outf, int K)
{
    __shared__ __bf16 As[64 * LDP];
    __shared__ __bf16 Bs[64 * LDP];
    int tid  = threadIdx.x;
    int lane = tid & 63;
    int w    = tid >> 6;
    int wm   = w >> 1, wn = w & 1;
    int quad = lane >> 4;
    int l16  = lane & 15;
    int m0 = blockIdx.y * 64;
    int n0 = blockIdx.x * 64;
    int lr = tid >> 2, lp = (tid & 3) * 8;

    f32x4 acc[2][2] = {};

    for (int kb = 0; kb < K; kb += 32) {
        bf16x8 areg = *(const bf16x8*)(A + (size_t)(m0 + lr) * K + kb + lp);
        bf16x8 breg = *(const bf16x8*)(B + (size_t)(n0 + lr) * K + kb + lp);
        __syncthreads();
        *(bf16x8*)(As + lr * LDP + lp) = areg;
        *(bf16x8*)(Bs + lr * LDP + lp) = breg;
        __syncthreads();
        bf16x8 af[2], bfr[2];
        #pragma unroll
        for (int mt = 0; mt < 2; ++mt)
            af[mt] = *(const bf16x8*)(As + (wm * 32 + mt * 16 + l16) * LDP + quad * 8);
        #pragma unroll
        for (int nt = 0; nt < 2; ++nt)
            bfr[nt] = *(const bf16x8*)(Bs + (wn * 32 + nt * 16 + l16) * LDP + quad * 8);
        #pragma unroll
        for (int mt = 0; mt < 2; ++mt)
            #pragma unroll
            for (int nt = 0; nt < 2; ++nt)
                acc[mt][nt] = __builtin_amdgcn_mfma_f32_16x16x32_bf16(
                    af[mt], bfr[nt], acc[mt][nt], 0, 0, 0);
    }

    int rowb = m0 + wm * 32;
    int colb = n0 + wn * 32;
    #pragma unroll
    for (int nt = 0; nt < 2; ++nt) {
        int col = colb + nt * 16 + l16;
        float bv = bias[col];
        #pragma unroll
        for (int mt = 0; mt < 2; ++mt) {
            int row = rowb + mt * 16 + quad * 4;
            #pragma unroll
            for (int r = 0; r < 4; ++r) {
                size_t off = (size_t)(row + r) * C_CH + col;
                outf[off] = acc[mt][nt][r] + bv + resid[off];
            }
        }
    }
}

// ---------------- CSR: scan + scatter ----------------
__global__ __launch_bounds__(1024) void scan_kernel(
    const int* __restrict__ deg, int* __restrict__ row_start)
{
    __shared__ int wsum[16];
    int tid = threadIdx.x;
    int lane = tid & 63, wid = tid >> 6;
    int base = tid * 16;
    int local[16];
    int run = 0;
    #pragma unroll
    for (int j = 0; j < 16; ++j) { local[j] = run; run += deg[base + j]; }
    int x = run;
    #pragma unroll
    for (int off = 1; off < 64; off <<= 1) {
        int y = __shfl_up(x, off);
        if (lane >= off) x += y;
    }
    if (lane == 63) wsum[wid] = x;
    __syncthreads();
    if (wid == 0) {
        int wv = (lane < 16) ? wsum[lane] : 0;
        int xx = wv;
        #pragma unroll
        for (int off = 1; off < 16; off <<= 1) {
            int y = __shfl_up(xx, off);
            if (lane >= off) xx += y;
        }
        if (lane < 16) wsum[lane] = xx - wv;
    }
    __syncthreads();
    int excl = wsum[wid] + (x - run);
    #pragma unroll
    for (int j = 0; j < 16; ++j) row_start[base + j] = excl + local[j];
    if (tid == 1023) row_start[N_NODES] = excl + run;
}

__global__ void scatter_kernel(const int* __restrict__ ei,
                               const int* __restrict__ row_start,
                               int* __restrict__ cnt, int* __restrict__ csr_src)
{
    int e = blockIdx.x * blockDim.x + threadIdx.x;
    if (e >= ETOT) return;
    int src, dst;
    if (e < E_EDGES) { src = ei[e]; dst = ei[E_EDGES + e]; }
    else             { src = dst = e - E_EDGES; }
    int pos = atomicAdd(cnt + dst, 1);
    csr_src[row_start[dst] + pos] = src;
}

// ---- fused softmax + aggregation, single pass (shift-invariant softmax;
//      logits are O(±8) so exp() is fp32-safe without max subtraction) ----
__global__ __launch_bounds__(256) void gat_fused(
    const __bf16* __restrict__ x_ln, const float* __restrict__ a_src,
    const float* __restrict__ a_dst, const int* __restrict__ row_start,
    const int* __restrict__ csr_src, __bf16* __restrict__ agg)
{
    int wave = threadIdx.x >> 6, lane = threadIdx.x & 63;
    int i = blockIdx.x * 4 + wave;
    int rs = row_start[i], deg = row_start[i + 1] - rs;
    float4 ad = *(const float4*)(a_dst + i * H_HEADS);

    float acc[4][4] = {};
    float sm0 = 0.f, sm1 = 0.f, sm2 = 0.f, sm3 = 0.f;
    for (int e = 0; e < deg; ++e) {
        int s = csr_src[rs + e];
        float4 as = *(const float4*)(a_src + s * H_HEADS);
        float l0 = as.x + ad.x, l1 = as.y + ad.y, l2 = as.z + ad.z, l3 = as.w + ad.w;
        l0 = (l0 > 0.f) ? l0 : 0.2f * l0;
        l1 = (l1 > 0.f) ? l1 : 0.2f * l1;
        l2 = (l2 > 0.f) ? l2 : 0.2f * l2;
        l3 = (l3 > 0.f) ? l3 : 0.2f * l3;
        float w0 = __expf(l0), w1 = __expf(l1);
        float w2 = __expf(l2), w3 = __expf(l3);
        sm0 += w0; sm1 += w1; sm2 += w2; sm3 += w3;
        bf16x4 x = *(const bf16x4*)(x_ln + (size_t)s * D_MODEL + lane * 4);
        #pragma unroll
        for (int j = 0; j < 4; ++j) {
            float xv = bf2f(x[j]);
            acc[0][j] = fmaf(w0, xv, acc[0][j]);
            acc[1][j] = fmaf(w1, xv, acc[1][j]);
            acc[2][j] = fmaf(w2, xv, acc[2][j]);
            acc[3][j] = fmaf(w3, xv, acc[3][j]);
        }
    }
    float sc[4] = {0.25f / sm0, 0.25f / sm1, 0.25f / sm2, 0.25f / sm3};
    #pragma unroll
    for (int h = 0; h < 4; ++h) {
        bf16x4 o;
        #pragma unroll
        for (int j = 0; j < 4; ++j) o[j] = f2bf(acc[h][j] * sc[h]);
        *(bf16x4*)(agg + (size_t)i * HC + h * 256 + lane * 4) = o;
    }
}

extern "C" void kernel_launch(void* const* d_in, const int* in_sizes, int n_in,
                              void* d_out, int out_size, void* d_ws, size_t ws_size,
                              hipStream_t stream)
{
    const float* inp      = (const float*)d_in[0];
    const int*   ei       = (const int*)  d_in[1];
    const float* ln_gamma = (const float*)d_in[2];
    const float* ln_beta  = (const float*)d_in[3];
    const float* W1       = (const float*)d_in[4];
    const float* b1       = (const float*)d_in[5];
    const float* W_gat    = (const float*)d_in[6];
    const float* att_src  = (const float*)d_in[7];
    const float* att_dst  = (const float*)d_in[8];
    const float* bias_gat = (const float*)d_in[9];
    const float* W2       = (const float*)d_in[10];
    const float* b2       = (const float*)d_in[11];

    char* ws = (char*)d_ws;
    __bf16* x_ln_bf   = (__bf16*)(ws);                        //  8 MB
    __bf16* agg_bf    = (__bf16*)(ws + (8ull  << 20));        // 32 MB
    float*  V_f       = (float*)(ws + (40ull << 20));         //  1 MB
    __bf16* Wz_b      = (__bf16*)(ws + (41ull << 20));        // 512 KB
    float*  a_src_b   = (float*)(ws + (42ull << 20));         // 256 KB
    float*  a_dst_b   = a_src_b + (size_t)N_NODES * H_HEADS;  // 256 KB
    // ---- zero region start ----
    float*  t_vec     = a_dst_b + (size_t)N_NODES * H_HEADS;  //  8 KB
    float*  u2        = t_vec + 8 * 256;                      //  8 KB
    float*  c0        = u2 + 8 * 256;                         //  32 B
    float*  bias_z    = c0 + 8;                               //  1 KB
    int*    deg       = (int*)(bias_z + 256);                 // 64 KB
    int*    cnt       = deg + N_NODES;                        // 64 KB
    // ---- zero region end ----
    int*    row_st    = cnt + N_NODES;
    int*    csr_src   = row_st + N_NODES + 4;

    size_t zbytes = (8 * 256 + 8 * 256 + 8 + 256) * sizeof(float)
                  + 2 * N_NODES * sizeof(int);
    hipMemsetAsync(t_vec, 0, zbytes, stream);

    // prep (2 launches) + CSR finish (2 launches)
    prep1<<<640, 256, 0, stream>>>(W_gat, att_src, att_dst, W2, ei, t_vec, V_f, deg);
    prep2<<<320, 256, 0, stream>>>(t_vec, W1, b1, V_f, W2, bias_gat, b2,
                                   u2, c0, Wz_b, bias_z);
    scan_kernel<<<1, 1024, 0, stream>>>(deg, row_st);
    scatter_kernel<<<(ETOT + 255) / 256, 256, 0, stream>>>(ei, row_st, cnt, csr_src);

    // dense pipeline: LN+logits -> softmax+aggregate -> single composite GEMM
    ln_logits<<<N_NODES / 4, 256, 0, stream>>>(inp, ln_gamma, ln_beta, u2, c0,
                                               x_ln_bf, a_src_b, a_dst_b);
    gat_fused<<<N_NODES / 4, 256, 0, stream>>>(x_ln_bf, a_src_b, a_dst_b,
                                               row_st, csr_src, agg_bf);
    gemm_skinny<<<dim3(C_CH / 64, N_NODES / 64), 256, 0, stream>>>(
        agg_bf, Wz_b, bias_z, inp, (float*)d_out, HC);
}

// Round 11
// 193.575 us; speedup vs baseline: 1.1578x; 1.0279x over previous
//
#include <hip/hip_runtime.h>
#include <math.h>

#define N_NODES 16384
#define D_MODEL 256
#define H_HEADS 4
#define C_CH 256
#define E_EDGES 65536
#define ETOT (E_EDGES + N_NODES)
#define HC 1024

typedef __bf16 bf16x8 __attribute__((ext_vector_type(8)));
typedef __bf16 bf16x4 __attribute__((ext_vector_type(4)));
typedef float f32x4 __attribute__((ext_vector_type(4)));

__device__ __forceinline__ __bf16 f2bf(float f) { return (__bf16)f; }
__device__ __forceinline__ float bf2f(__bf16 b) { return (float)b; }

// ==== prep1: blocks 0..63 t-partials | 64..319 compose_v | 320..639 hist ====
__global__ __launch_bounds__(256) void prep1(
    const float* __restrict__ Wg, const float* __restrict__ att_src,
    const float* __restrict__ att_dst, const float* __restrict__ W2,
    const int* __restrict__ ei, float* __restrict__ t,
    float* __restrict__ V, int* __restrict__ deg)
{
    int b = blockIdx.x;
    int tid = threadIdx.x;
    if (b < 64) {
        int v = b >> 3, sl = b & 7, h = v & 3;
        const float* att = ((v < 4) ? att_src : att_dst) + h * C_CH;
        float acc = 0.f;
        #pragma unroll
        for (int j = 0; j < 32; ++j) {
            int c = sl * 32 + j;
            acc = fmaf(Wg[(size_t)(h * 256 + c) * 256 + tid], att[c], acc);
        }
        atomicAdd(&t[v * 256 + tid], acc);
    } else if (b < 320) {
        int bb = b - 64;
        int og = (bb & 63) * 4, h = bb >> 6;
        const float* w2r = W2 + (size_t)og * 256;
        const float* wgp = Wg + ((size_t)h * 256) * 256 + tid;
        float a0 = 0.f, a1 = 0.f, a2 = 0.f, a3 = 0.f;
        #pragma unroll 4
        for (int c = 0; c < 256; ++c) {
            float wv = wgp[(size_t)c * 256];
            a0 = fmaf(w2r[c],       wv, a0);
            a1 = fmaf(w2r[256 + c], wv, a1);
            a2 = fmaf(w2r[512 + c], wv, a2);
            a3 = fmaf(w2r[768 + c], wv, a3);
        }
        size_t base = (size_t)og * 1024 + h * 256 + tid;
        V[base]        = a0;
        V[base + 1024] = a1;
        V[base + 2048] = a2;
        V[base + 3072] = a3;
    } else {
        int e = (b - 320) * 256 + tid;
        int dst = (e < E_EDGES) ? ei[E_EDGES + e] : (e - E_EDGES);
        atomicAdd(deg + dst, 1);
    }
}

// ==== prep2: blocks 0..63 u2/c0 | 64..319 compose_wz + bias_z | 320 scan ====
__global__ __launch_bounds__(256) void prep2(
    const float* __restrict__ t, const float* __restrict__ W1,
    const float* __restrict__ b1, const float* __restrict__ V,
    const float* __restrict__ W2, const float* __restrict__ bg,
    const float* __restrict__ b2, float* __restrict__ u2,
    float* __restrict__ c0, __bf16* __restrict__ Wz,
    float* __restrict__ bias_z, const int* __restrict__ deg,
    int* __restrict__ row_st)
{
    int b = blockIdx.x;
    int d = threadIdx.x;
    if (b < 64) {
        int v = b >> 3, sl = b & 7;
        const float* tv = t + v * 256;
        float acc = 0.f;
        #pragma unroll
        for (int j = 0; j < 32; ++j) {
            int k = sl * 32 + j;
            acc = fmaf(tv[k], W1[(size_t)k * 256 + d], acc);
        }
        atomicAdd(&u2[v * 256 + d], acc);
        if (d < 32) {
            float p = tv[sl * 32 + d] * b1[sl * 32 + d];
            for (int s = 16; s; s >>= 1) p += __shfl_xor(p, s);
            if (d == 0) atomicAdd(&c0[v], p);
        }
        return;
    }
    if (b == 320) {
        // exclusive scan of deg[16384] with 256 threads x 64 elems, two-pass
        __shared__ int wsum[4];
        int lane = d & 63, wid = d >> 6;
        int base = d * 64;
        int run = 0;
        for (int j = 0; j < 64; ++j) run += deg[base + j];
        int x = run;
        #pragma unroll
        for (int off = 1; off < 64; off <<= 1) {
            int y = __shfl_up(x, off);
            if (lane >= off) x += y;
        }
        if (lane == 63) wsum[wid] = x;
        __syncthreads();
        int woff = 0;
        #pragma unroll
        for (int wdx = 0; wdx < 4; ++wdx)
            if (wdx < wid) woff += wsum[wdx];
        int excl = woff + x - run;     // exclusive prefix of this thread's chunk
        int run2 = 0;
        for (int j = 0; j < 64; ++j) {
            row_st[base + j] = excl + run2;
            run2 += deg[base + j];
        }
        if (d == 255) row_st[N_NODES] = excl + run2;
        return;
    }
    int bb = b - 64;
    int og = (bb & 63) * 4, h = bb >> 6;
    int lane = d & 63, wid = d >> 6;
    const float* vr = V + (size_t)og * 1024 + h * 256;
    float a0 = 0.f, a1 = 0.f, a2 = 0.f, a3 = 0.f;
    #pragma unroll 4
    for (int k = 0; k < 256; ++k) {
        float w1v = W1[(size_t)k * 256 + d];
        a0 = fmaf(vr[k],        w1v, a0);
        a1 = fmaf(vr[1024 + k], w1v, a1);
        a2 = fmaf(vr[2048 + k], w1v, a2);
        a3 = fmaf(vr[3072 + k], w1v, a3);
    }
    size_t base = (size_t)og * 1024 + h * 256 + d;
    Wz[base]        = f2bf(a0);
    Wz[base + 1024] = f2bf(a1);
    Wz[base + 2048] = f2bf(a2);
    Wz[base + 3072] = f2bf(a3);

    __shared__ float red[4][4];
    float b1v = b1[d];
    #pragma unroll
    for (int j = 0; j < 4; ++j) {
        float p = vr[(size_t)j * 1024 + d] * b1v;
        for (int s = 32; s; s >>= 1) p += __shfl_xor(p, s);
        if (lane == 0) red[j][wid] = p;
    }
    __syncthreads();
    if (d < 4) {
        float s = red[d][0] + red[d][1] + red[d][2] + red[d][3];
        atomicAdd(&bias_z[og + d], 0.25f * s);
    }
    if (h == 0) {
        __syncthreads();
        float bgv = bg[d];
        #pragma unroll
        for (int j = 0; j < 4; ++j) {
            float q = W2[(size_t)(og + j) * 256 + d] * bgv;
            for (int s = 32; s; s >>= 1) q += __shfl_xor(q, s);
            if (lane == 0) red[j][wid] = q;
        }
        __syncthreads();
        if (d < 4) {
            float s = red[d][0] + red[d][1] + red[d][2] + red[d][3];
            atomicAdd(&bias_z[og + d], s + b2[og + d]);
        }
    }
}

// ==== ln_scatter: blocks 0..4095 LayerNorm+logits | 4096..4415 CSR scatter ====
__global__ __launch_bounds__(256) void ln_scatter(
    const float* __restrict__ in, const float* __restrict__ gamma,
    const float* __restrict__ beta, const float* __restrict__ u2,
    const float* __restrict__ c0, __bf16* __restrict__ out,
    float* __restrict__ a_src, float* __restrict__ a_dst,
    const int* __restrict__ ei, const int* __restrict__ row_st,
    int* __restrict__ cnt, int* __restrict__ csr_src)
{
    int b = blockIdx.x;
    int tid = threadIdx.x;
    if (b >= 4096) {
        int e = (b - 4096) * 256 + tid;
        int src, dst;
        if (e < E_EDGES) { src = ei[e]; dst = ei[E_EDGES + e]; }
        else             { src = dst = e - E_EDGES; }
        int pos = atomicAdd(cnt + dst, 1);
        csr_src[row_st[dst] + pos] = src;
        return;
    }
    __shared__ float u2s[8][256];
    __shared__ float c0s[8];
    #pragma unroll
    for (int t = 0; t < 8; ++t) u2s[t][tid] = u2[t * 256 + tid];
    if (tid < 8) c0s[tid] = c0[tid];
    __syncthreads();

    int wave = tid >> 6, lane = tid & 63;
    int row = b * 4 + wave;
    float4 v = ((const float4*)(in + (size_t)row * D_MODEL))[lane];
    float s  = v.x + v.y + v.z + v.w;
    float sq = v.x*v.x + v.y*v.y + v.z*v.z + v.w*v.w;
    for (int off = 32; off; off >>= 1) {
        s  += __shfl_xor(s,  off);
        sq += __shfl_xor(sq, off);
    }
    float mean = s * (1.0f / D_MODEL);
    float var  = sq * (1.0f / D_MODEL) - mean * mean;
    float inv  = rsqrtf(var + 1e-6f);
    float4 g = ((const float4*)gamma)[lane];
    float4 bb = ((const float4*)beta)[lane];
    float x0 = (v.x - mean) * inv * g.x + bb.x;
    float x1 = (v.y - mean) * inv * g.y + bb.y;
    float x2 = (v.z - mean) * inv * g.z + bb.z;
    float x3 = (v.w - mean) * inv * g.w + bb.w;
    bf16x4 o;
    o[0] = f2bf(x0); o[1] = f2bf(x1); o[2] = f2bf(x2); o[3] = f2bf(x3);
    *(bf16x4*)(out + (size_t)row * D_MODEL + lane * 4) = o;

    float p[8];
    #pragma unroll
    for (int k = 0; k < 8; ++k) {
        const float* up = &u2s[k][lane * 4];
        p[k] = x0 * up[0] + x1 * up[1] + x2 * up[2] + x3 * up[3];
    }
    #pragma unroll
    for (int k = 0; k < 8; ++k)
        for (int s2 = 32; s2; s2 >>= 1) p[k] += __shfl_xor(p[k], s2);
    if (lane == 0) {
        f32x4 ps = {p[0] + c0s[0], p[1] + c0s[1], p[2] + c0s[2], p[3] + c0s[3]};
        f32x4 pd = {p[4] + c0s[4], p[5] + c0s[5], p[6] + c0s[6], p[7] + c0s[7]};
        *(f32x4*)(a_src + row * H_HEADS) = ps;
        *(f32x4*)(a_dst + row * H_HEADS) = pd;
    }
}

// ---- fused softmax + aggregation, single pass (shift-invariant softmax) ----
__global__ __launch_bounds__(256) void gat_fused(
    const __bf16* __restrict__ x_ln, const float* __restrict__ a_src,
    const float* __restrict__ a_dst, const int* __restrict__ row_start,
    const int* __restrict__ csr_src, __bf16* __restrict__ agg)
{
    int wave = threadIdx.x >> 6, lane = threadIdx.x & 63;
    int i = blockIdx.x * 4 + wave;
    int rs = row_start[i], deg = row_start[i + 1] - rs;
    float4 ad = *(const float4*)(a_dst + i * H_HEADS);

    float acc[4][4] = {};
    float sm0 = 0.f, sm1 = 0.f, sm2 = 0.f, sm3 = 0.f;
    for (int e = 0; e < deg; ++e) {
        int s = csr_src[rs + e];
        float4 as = *(const float4*)(a_src + s * H_HEADS);
        float l0 = as.x + ad.x, l1 = as.y + ad.y, l2 = as.z + ad.z, l3 = as.w + ad.w;
        l0 = (l0 > 0.f) ? l0 : 0.2f * l0;
        l1 = (l1 > 0.f) ? l1 : 0.2f * l1;
        l2 = (l2 > 0.f) ? l2 : 0.2f * l2;
        l3 = (l3 > 0.f) ? l3 : 0.2f * l3;
        float w0 = __expf(l0), w1 = __expf(l1);
        float w2 = __expf(l2), w3 = __expf(l3);
        sm0 += w0; sm1 += w1; sm2 += w2; sm3 += w3;
        bf16x4 x = *(const bf16x4*)(x_ln + (size_t)s * D_MODEL + lane * 4);
        #pragma unroll
        for (int j = 0; j < 4; ++j) {
            float xv = bf2f(x[j]);
            acc[0][j] = fmaf(w0, xv, acc[0][j]);
            acc[1][j] = fmaf(w1, xv, acc[1][j]);
            acc[2][j] = fmaf(w2, xv, acc[2][j]);
            acc[3][j] = fmaf(w3, xv, acc[3][j]);
        }
    }
    float sc[4] = {0.25f / sm0, 0.25f / sm1, 0.25f / sm2, 0.25f / sm3};
    #pragma unroll
    for (int h = 0; h < 4; ++h) {
        bf16x4 o;
        #pragma unroll
        for (int j = 0; j < 4; ++j) o[j] = f2bf(acc[h][j] * sc[h]);
        *(bf16x4*)(agg + (size_t)i * HC + h * 256 + lane * 4) = o;
    }
}

// -------- skinny bf16 GEMM: out[M,256] = A[M,K]·B[256,K]^T + bias + resid --------
#define LDP 40   // LDS row stride (80B): max 2-way bank aliasing (free)

__global__ __launch_bounds__(256) void gemm_skinny(
    const __bf16* __restrict__ A, const __bf16* __restrict__ B,
    const float* __restrict__ bias, const float* __restrict__ resid,
    float* __restrict__ outf, int K)
{
    __shared__ __bf16 As[64 * LDP];
    __shared__ __bf16 Bs[64 * LDP];
    int tid  = threadIdx.x;
    int lane = tid & 63;
    int w    = tid >> 6;
    int wm   = w >> 1, wn = w & 1;
    int quad = lane >> 4;
    int l16  = lane & 15;
    int m0 = blockIdx.y * 64;
    int n0 = blockIdx.x * 64;
    int lr = tid >> 2, lp = (tid & 3) * 8;

    f32x4 acc[2][2] = {};

    for (int kb = 0; kb < K; kb += 32) {
        bf16x8 areg = *(const bf16x8*)(A + (size_t)(m0 + lr) * K + kb + lp);
        bf16x8 breg = *(const bf16x8*)(B + (size_t)(n0 + lr) * K + kb + lp);
        __syncthreads();
        *(bf16x8*)(As + lr * LDP + lp) = areg;
        *(bf16x8*)(Bs + lr * LDP + lp) = breg;
        __syncthreads();
        bf16x8 af[2], bfr[2];
        #pragma unroll
        for (int mt = 0; mt < 2; ++mt)
            af[mt] = *(const bf16x8*)(As + (wm * 32 + mt * 16 + l16) * LDP + quad * 8);
        #pragma unroll
        for (int nt = 0; nt < 2; ++nt)
            bfr[nt] = *(const bf16x8*)(Bs + (wn * 32 + nt * 16 + l16) * LDP + quad * 8);
        #pragma unroll
        for (int mt = 0; mt < 2; ++mt)
            #pragma unroll
            for (int nt = 0; nt < 2; ++nt)
                acc[mt][nt] = __builtin_amdgcn_mfma_f32_16x16x32_bf16(
                    af[mt], bfr[nt], acc[mt][nt], 0, 0, 0);
    }

    int rowb = m0 + wm * 32;
    int colb = n0 + wn * 32;
    #pragma unroll
    for (int nt = 0; nt < 2; ++nt) {
        int col = colb + nt * 16 + l16;
        float bv = bias[col];
        #pragma unroll
        for (int mt = 0; mt < 2; ++mt) {
            int row = rowb + mt * 16 + quad * 4;
            #pragma unroll
            for (int r = 0; r < 4; ++r) {
                size_t off = (size_t)(row + r) * C_CH + col;
                outf[off] = acc[mt][nt][r] + bv + resid[off];
            }
        }
    }
}

extern "C" void kernel_launch(void* const* d_in, const int* in_sizes, int n_in,
                              void* d_out, int out_size, void* d_ws, size_t ws_size,
                              hipStream_t stream)
{
    const float* inp      = (const float*)d_in[0];
    const int*   ei       = (const int*)  d_in[1];
    const float* ln_gamma = (const float*)d_in[2];
    const float* ln_beta  = (const float*)d_in[3];
    const float* W1       = (const float*)d_in[4];
    const float* b1       = (const float*)d_in[5];
    const float* W_gat    = (const float*)d_in[6];
    const float* att_src  = (const float*)d_in[7];
    const float* att_dst  = (const float*)d_in[8];
    const float* bias_gat = (const float*)d_in[9];
    const float* W2       = (const float*)d_in[10];
    const float* b2       = (const float*)d_in[11];

    char* ws = (char*)d_ws;
    __bf16* x_ln_bf   = (__bf16*)(ws);                        //  8 MB
    __bf16* agg_bf    = (__bf16*)(ws + (8ull  << 20));        // 32 MB
    float*  V_f       = (float*)(ws + (40ull << 20));         //  1 MB
    __bf16* Wz_b      = (__bf16*)(ws + (41ull << 20));        // 512 KB
    float*  a_src_b   = (float*)(ws + (42ull << 20));         // 256 KB
    float*  a_dst_b   = a_src_b + (size_t)N_NODES * H_HEADS;  // 256 KB
    // ---- zero region start ----
    float*  t_vec     = a_dst_b + (size_t)N_NODES * H_HEADS;  //  8 KB
    float*  u2        = t_vec + 8 * 256;                      //  8 KB
    float*  c0        = u2 + 8 * 256;                         //  32 B
    float*  bias_z    = c0 + 8;                               //  1 KB
    int*    deg       = (int*)(bias_z + 256);                 // 64 KB
    int*    cnt       = deg + N_NODES;                        // 64 KB
    // ---- zero region end ----
    int*    row_st    = cnt + N_NODES;
    int*    csr_src   = row_st + N_NODES + 4;

    size_t zbytes = (8 * 256 + 8 * 256 + 8 + 256) * sizeof(float)
                  + 2 * N_NODES * sizeof(int);
    hipMemsetAsync(t_vec, 0, zbytes, stream);

    // prep chain (scan hidden in prep2; scatter hidden in ln launch)
    prep1<<<640, 256, 0, stream>>>(W_gat, att_src, att_dst, W2, ei, t_vec, V_f, deg);
    prep2<<<321, 256, 0, stream>>>(t_vec, W1, b1, V_f, W2, bias_gat, b2,
                                   u2, c0, Wz_b, bias_z, deg, row_st);
    ln_scatter<<<4096 + 320, 256, 0, stream>>>(inp, ln_gamma, ln_beta, u2, c0,
                                               x_ln_bf, a_src_b, a_dst_b,
                                               ei, row_st, cnt, csr_src);
    gat_fused<<<N_NODES / 4, 256, 0, stream>>>(x_ln_bf, a_src_b, a_dst_b,
                                               row_st, csr_src, agg_bf);
    gemm_skinny<<<dim3(C_CH / 64, N_NODES / 64), 256, 0, stream>>>(
        agg_bf, Wz_b, bias_z, inp, (float*)d_out, HC);
}

// Round 13
// 189.135 us; speedup vs baseline: 1.1850x; 1.0235x over previous
//
#include <hip/hip_runtime.h>
#include <math.h>

#define N_NODES 16384
#define D_MODEL 256
#define H_HEADS 4
#define C_CH 256
#define E_EDGES 65536
#define ETOT (E_EDGES + N_NODES)
#define HC 1024

typedef __bf16 bf16x8 __attribute__((ext_vector_type(8)));
typedef __bf16 bf16x4 __attribute__((ext_vector_type(4)));
typedef float f32x4 __attribute__((ext_vector_type(4)));

__device__ __forceinline__ __bf16 f2bf(float f) { return (__bf16)f; }
__device__ __forceinline__ float bf2f(__bf16 b) { return (float)b; }

// ==== prep1_ln: 0..63 t-partials | 64..319 compose_v | 320..639 hist |
//                640..4735 LayerNorm (independent of prep outputs) ====
__global__ __launch_bounds__(256) void prep1_ln(
    const float* __restrict__ Wg, const float* __restrict__ att_src,
    const float* __restrict__ att_dst, const float* __restrict__ W2,
    const int* __restrict__ ei, const float* __restrict__ in,
    const float* __restrict__ gamma, const float* __restrict__ beta,
    float* __restrict__ t, float* __restrict__ V, int* __restrict__ deg,
    __bf16* __restrict__ x_ln)
{
    int b = blockIdx.x;
    int tid = threadIdx.x;
    if (b >= 640) {
        // LayerNorm: one row per wave
        int wave = tid >> 6, lane = tid & 63;
        int row = (b - 640) * 4 + wave;
        float4 v = ((const float4*)(in + (size_t)row * D_MODEL))[lane];
        float s  = v.x + v.y + v.z + v.w;
        float sq = v.x*v.x + v.y*v.y + v.z*v.z + v.w*v.w;
        for (int off = 32; off; off >>= 1) {
            s  += __shfl_xor(s,  off);
            sq += __shfl_xor(sq, off);
        }
        float mean = s * (1.0f / D_MODEL);
        float var  = sq * (1.0f / D_MODEL) - mean * mean;
        float inv  = rsqrtf(var + 1e-6f);
        float4 g = ((const float4*)gamma)[lane];
        float4 bb = ((const float4*)beta)[lane];
        bf16x4 o;
        o[0] = f2bf((v.x - mean) * inv * g.x + bb.x);
        o[1] = f2bf((v.y - mean) * inv * g.y + bb.y);
        o[2] = f2bf((v.z - mean) * inv * g.z + bb.z);
        o[3] = f2bf((v.w - mean) * inv * g.w + bb.w);
        *(bf16x4*)(x_ln + (size_t)row * D_MODEL + lane * 4) = o;
        return;
    }
    if (b < 64) {
        int v = b >> 3, sl = b & 7, h = v & 3;
        const float* att = ((v < 4) ? att_src : att_dst) + h * C_CH;
        float acc = 0.f;
        #pragma unroll
        for (int j = 0; j < 32; ++j) {
            int c = sl * 32 + j;
            acc = fmaf(Wg[(size_t)(h * 256 + c) * 256 + tid], att[c], acc);
        }
        atomicAdd(&t[v * 256 + tid], acc);
    } else if (b < 320) {
        int bb = b - 64;
        int og = (bb & 63) * 4, h = bb >> 6;
        const float* w2r = W2 + (size_t)og * 256;
        const float* wgp = Wg + ((size_t)h * 256) * 256 + tid;
        float a0 = 0.f, a1 = 0.f, a2 = 0.f, a3 = 0.f;
        #pragma unroll 4
        for (int c = 0; c < 256; ++c) {
            float wv = wgp[(size_t)c * 256];
            a0 = fmaf(w2r[c],       wv, a0);
            a1 = fmaf(w2r[256 + c], wv, a1);
            a2 = fmaf(w2r[512 + c], wv, a2);
            a3 = fmaf(w2r[768 + c], wv, a3);
        }
        size_t base = (size_t)og * 1024 + h * 256 + tid;
        V[base]        = a0;
        V[base + 1024] = a1;
        V[base + 2048] = a2;
        V[base + 3072] = a3;
    } else {
        int e = (b - 320) * 256 + tid;
        int dst = (e < E_EDGES) ? ei[E_EDGES + e] : (e - E_EDGES);
        atomicAdd(deg + dst, 1);
    }
}

// ==== prep2: blocks 0..63 u2/c0 | 64..319 compose_wz + bias_z | 320 scan ====
__global__ __launch_bounds__(256) void prep2(
    const float* __restrict__ t, const float* __restrict__ W1,
    const float* __restrict__ b1, const float* __restrict__ V,
    const float* __restrict__ W2, const float* __restrict__ bg,
    const float* __restrict__ b2, float* __restrict__ u2,
    float* __restrict__ c0, __bf16* __restrict__ Wz,
    float* __restrict__ bias_z, const int* __restrict__ deg,
    int* __restrict__ row_st)
{
    int b = blockIdx.x;
    int d = threadIdx.x;
    if (b < 64) {
        int v = b >> 3, sl = b & 7;
        const float* tv = t + v * 256;
        float acc = 0.f;
        #pragma unroll
        for (int j = 0; j < 32; ++j) {
            int k = sl * 32 + j;
            acc = fmaf(tv[k], W1[(size_t)k * 256 + d], acc);
        }
        atomicAdd(&u2[v * 256 + d], acc);
        if (d < 32) {
            float p = tv[sl * 32 + d] * b1[sl * 32 + d];
            for (int s = 16; s; s >>= 1) p += __shfl_xor(p, s);
            if (d == 0) atomicAdd(&c0[v], p);
        }
        return;
    }
    if (b == 320) {
        __shared__ int wsum[4];
        int lane = d & 63, wid = d >> 6;
        int base = d * 64;
        int run = 0;
        for (int j = 0; j < 64; ++j) run += deg[base + j];
        int x = run;
        #pragma unroll
        for (int off = 1; off < 64; off <<= 1) {
            int y = __shfl_up(x, off);
            if (lane >= off) x += y;
        }
        if (lane == 63) wsum[wid] = x;
        __syncthreads();
        int woff = 0;
        #pragma unroll
        for (int wdx = 0; wdx < 4; ++wdx)
            if (wdx < wid) woff += wsum[wdx];
        int excl = woff + x - run;
        int run2 = 0;
        for (int j = 0; j < 64; ++j) {
            row_st[base + j] = excl + run2;
            run2 += deg[base + j];
        }
        if (d == 255) row_st[N_NODES] = excl + run2;
        return;
    }
    int bb = b - 64;
    int og = (bb & 63) * 4, h = bb >> 6;
    int lane = d & 63, wid = d >> 6;
    const float* vr = V + (size_t)og * 1024 + h * 256;
    float a0 = 0.f, a1 = 0.f, a2 = 0.f, a3 = 0.f;
    #pragma unroll 4
    for (int k = 0; k < 256; ++k) {
        float w1v = W1[(size_t)k * 256 + d];
        a0 = fmaf(vr[k],        w1v, a0);
        a1 = fmaf(vr[1024 + k], w1v, a1);
        a2 = fmaf(vr[2048 + k], w1v, a2);
        a3 = fmaf(vr[3072 + k], w1v, a3);
    }
    size_t base = (size_t)og * 1024 + h * 256 + d;
    Wz[base]        = f2bf(a0);
    Wz[base + 1024] = f2bf(a1);
    Wz[base + 2048] = f2bf(a2);
    Wz[base + 3072] = f2bf(a3);

    __shared__ float red[4][4];
    float b1v = b1[d];
    #pragma unroll
    for (int j = 0; j < 4; ++j) {
        float p = vr[(size_t)j * 1024 + d] * b1v;
        for (int s = 32; s; s >>= 1) p += __shfl_xor(p, s);
        if (lane == 0) red[j][wid] = p;
    }
    __syncthreads();
    if (d < 4) {
        float s = red[d][0] + red[d][1] + red[d][2] + red[d][3];
        atomicAdd(&bias_z[og + d], 0.25f * s);
    }
    if (h == 0) {
        __syncthreads();
        float bgv = bg[d];
        #pragma unroll
        for (int j = 0; j < 4; ++j) {
            float q = W2[(size_t)(og + j) * 256 + d] * bgv;
            for (int s = 32; s; s >>= 1) q += __shfl_xor(q, s);
            if (lane == 0) red[j][wid] = q;
        }
        __syncthreads();
        if (d < 4) {
            float s = red[d][0] + red[d][1] + red[d][2] + red[d][3];
            atomicAdd(&bias_z[og + d], s + b2[og + d]);
        }
    }
}

// ==== logits_scatter: blocks 0..4095 logits (wave/node) | 4096..4415 scatter ====
__global__ __launch_bounds__(256) void logits_scatter(
    const __bf16* __restrict__ x_ln, const float* __restrict__ u2,
    const float* __restrict__ c0, float* __restrict__ a_src,
    float* __restrict__ a_dst, const int* __restrict__ ei,
    const int* __restrict__ row_st, int* __restrict__ cnt,
    int* __restrict__ csr_src)
{
    int b = blockIdx.x;
    int tid = threadIdx.x;
    if (b >= 4096) {
        int e = (b - 4096) * 256 + tid;
        int src, dst;
        if (e < E_EDGES) { src = ei[e]; dst = ei[E_EDGES + e]; }
        else             { src = dst = e - E_EDGES; }
        int pos = atomicAdd(cnt + dst, 1);
        csr_src[row_st[dst] + pos] = src;
        return;
    }
    __shared__ float u2s[8][256];
    __shared__ float c0s[8];
    #pragma unroll
    for (int k = 0; k < 8; ++k) u2s[k][tid] = u2[k * 256 + tid];
    if (tid < 8) c0s[tid] = c0[tid];
    __syncthreads();

    // wave per node; lane = v*8 + p, p covers 32 channels
    int wave = tid >> 6, lane = tid & 63;
    int n = b * 4 + wave;
    int v = lane >> 3, p = lane & 7;
    const __bf16* xp = x_ln + (size_t)n * D_MODEL + p * 32;
    const float*  up = &u2s[v][p * 32];
    float acc = 0.f;
    #pragma unroll
    for (int ti = 0; ti < 4; ++ti) {
        bf16x8 x = *(const bf16x8*)(xp + ti * 8);
        #pragma unroll
        for (int j = 0; j < 8; ++j)
            acc = fmaf(bf2f(x[j]), up[ti * 8 + j], acc);
    }
    acc += __shfl_xor(acc, 1);
    acc += __shfl_xor(acc, 2);
    acc += __shfl_xor(acc, 4);
    if (p == 0) {
        float o = acc + c0s[v];
        if (v < 4) a_src[n * H_HEADS + v] = o;
        else       a_dst[n * H_HEADS + (v - 4)] = o;
    }
}

// ---- fused softmax + aggregation, single pass (shift-invariant softmax) ----
__global__ __launch_bounds__(256) void gat_fused(
    const __bf16* __restrict__ x_ln, const float* __restrict__ a_src,
    const float* __restrict__ a_dst, const int* __restrict__ row_start,
    const int* __restrict__ csr_src, __bf16* __restrict__ agg)
{
    int wave = threadIdx.x >> 6, lane = threadIdx.x & 63;
    int i = blockIdx.x * 4 + wave;
    int rs = row_start[i], deg = row_start[i + 1] - rs;
    float4 ad = *(const float4*)(a_dst + i * H_HEADS);

    float acc[4][4] = {};
    float sm0 = 0.f, sm1 = 0.f, sm2 = 0.f, sm3 = 0.f;
    for (int e = 0; e < deg; ++e) {
        int s = csr_src[rs + e];
        float4 as = *(const float4*)(a_src + s * H_HEADS);
        float l0 = as.x + ad.x, l1 = as.y + ad.y, l2 = as.z + ad.z, l3 = as.w + ad.w;
        l0 = (l0 > 0.f) ? l0 : 0.2f * l0;
        l1 = (l1 > 0.f) ? l1 : 0.2f * l1;
        l2 = (l2 > 0.f) ? l2 : 0.2f * l2;
        l3 = (l3 > 0.f) ? l3 : 0.2f * l3;
        float w0 = __expf(l0), w1 = __expf(l1);
        float w2 = __expf(l2), w3 = __expf(l3);
        sm0 += w0; sm1 += w1; sm2 += w2; sm3 += w3;
        bf16x4 x = *(const bf16x4*)(x_ln + (size_t)s * D_MODEL + lane * 4);
        #pragma unroll
        for (int j = 0; j < 4; ++j) {
            float xv = bf2f(x[j]);
            acc[0][j] = fmaf(w0, xv, acc[0][j]);
            acc[1][j] = fmaf(w1, xv, acc[1][j]);
            acc[2][j] = fmaf(w2, xv, acc[2][j]);
            acc[3][j] = fmaf(w3, xv, acc[3][j]);
        }
    }
    float sc[4] = {0.25f / sm0, 0.25f / sm1, 0.25f / sm2, 0.25f / sm3};
    #pragma unroll
    for (int h = 0; h < 4; ++h) {
        bf16x4 o;
        #pragma unroll
        for (int j = 0; j < 4; ++j) o[j] = f2bf(acc[h][j] * sc[h]);
        *(bf16x4*)(agg + (size_t)i * HC + h * 256 + lane * 4) = o;
    }
}

// -------- skinny bf16 GEMM: out[M,256] = A[M,K]·B[256,K]^T + bias + resid --------
#define LDP 40   // LDS row stride (80B): max 2-way bank aliasing (free)

__global__ __launch_bounds__(256) void gemm_skinny(
    const __bf16* __restrict__ A, const __bf16* __restrict__ B,
    const float* __restrict__ bias, const float* __restrict__ resid,
    float* __restrict__ outf, int K)
{
    __shared__ __bf16 As[64 * LDP];
    __shared__ __bf16 Bs[64 * LDP];
    int tid  = threadIdx.x;
    int lane = tid & 63;
    int w    = tid >> 6;
    int wm   = w >> 1, wn = w & 1;
    int quad = lane >> 4;
    int l16  = lane & 15;
    int m0 = blockIdx.y * 64;
    int n0 = blockIdx.x * 64;
    int lr = tid >> 2, lp = (tid & 3) * 8;

    f32x4 acc[2][2] = {};

    for (int kb = 0; kb < K; kb += 32) {
        bf16x8 areg = *(const bf16x8*)(A + (size_t)(m0 + lr) * K + kb + lp);
        bf16x8 breg = *(const bf16x8*)(B + (size_t)(n0 + lr) * K + kb + lp);
        __syncthreads();
        *(bf16x8*)(As + lr * LDP + lp) = areg;
        *(bf16x8*)(Bs + lr * LDP + lp) = breg;
        __syncthreads();
        bf16x8 af[2], bfr[2];
        #pragma unroll
        for (int mt = 0; mt < 2; ++mt)
            af[mt] = *(const bf16x8*)(As + (wm * 32 + mt * 16 + l16) * LDP + quad * 8);
        #pragma unroll
        for (int nt = 0; nt < 2; ++nt)
            bfr[nt] = *(const bf16x8*)(Bs + (wn * 32 + nt * 16 + l16) * LDP + quad * 8);
        #pragma unroll
        for (int mt = 0; mt < 2; ++mt)
            #pragma unroll
            for (int nt = 0; nt < 2; ++nt)
                acc[mt][nt] = __builtin_amdgcn_mfma_f32_16x16x32_bf16(
                    af[mt], bfr[nt], acc[mt][nt], 0, 0, 0);
    }

    int rowb = m0 + wm * 32;
    int colb = n0 + wn * 32;
    #pragma unroll
    for (int nt = 0; nt < 2; ++nt) {
        int col = colb + nt * 16 + l16;
        float bv = bias[col];
        #pragma unroll
        for (int mt = 0; mt < 2; ++mt) {
            int row = rowb + mt * 16 + quad * 4;
            #pragma unroll
            for (int r = 0; r < 4; ++r) {
                size_t off = (size_t)(row + r) * C_CH + col;
                outf[off] = acc[mt][nt][r] + bv + resid[off];
            }
        }
    }
}

extern "C" void kernel_launch(void* const* d_in, const int* in_sizes, int n_in,
                              void* d_out, int out_size, void* d_ws, size_t ws_size,
                              hipStream_t stream)
{
    const float* inp      = (const float*)d_in[0];
    const int*   ei       = (const int*)  d_in[1];
    const float* ln_gamma = (const float*)d_in[2];
    const float* ln_beta  = (const float*)d_in[3];
    const float* W1       = (const float*)d_in[4];
    const float* b1       = (const float*)d_in[5];
    const float* W_gat    = (const float*)d_in[6];
    const float* att_src  = (const float*)d_in[7];
    const float* att_dst  = (const float*)d_in[8];
    const float* bias_gat = (const float*)d_in[9];
    const float* W2       = (const float*)d_in[10];
    const float* b2       = (const float*)d_in[11];

    char* ws = (char*)d_ws;
    __bf16* x_ln_bf   = (__bf16*)(ws);                        //  8 MB
    __bf16* agg_bf    = (__bf16*)(ws + (8ull  << 20));        // 32 MB
    float*  V_f       = (float*)(ws + (40ull << 20));         //  1 MB
    __bf16* Wz_b      = (__bf16*)(ws + (41ull << 20));        // 512 KB
    float*  a_src_b   = (float*)(ws + (42ull << 20));         // 256 KB
    float*  a_dst_b   = a_src_b + (size_t)N_NODES * H_HEADS;  // 256 KB
    // ---- zero region start ----
    float*  t_vec     = a_dst_b + (size_t)N_NODES * H_HEADS;  //  8 KB
    float*  u2        = t_vec + 8 * 256;                      //  8 KB
    float*  c0        = u2 + 8 * 256;                         //  32 B
    float*  bias_z    = c0 + 8;                               //  1 KB
    int*    deg       = (int*)(bias_z + 256);                 // 64 KB
    int*    cnt       = deg + N_NODES;                        // 64 KB
    // ---- zero region end ----
    int*    row_st    = cnt + N_NODES;
    int*    csr_src   = row_st + N_NODES + 4;

    size_t zbytes = (8 * 256 + 8 * 256 + 8 + 256) * sizeof(float)
                  + 2 * N_NODES * sizeof(int);
    hipMemsetAsync(t_vec, 0, zbytes, stream);

    // prep1 + LayerNorm overlapped; prep2 + scan; logits + scatter
    prep1_ln<<<640 + 4096, 256, 0, stream>>>(W_gat, att_src, att_dst, W2, ei,
                                             inp, ln_gamma, ln_beta,
                                             t_vec, V_f, deg, x_ln_bf);
    prep2<<<321, 256, 0, stream>>>(t_vec, W1, b1, V_f, W2, bias_gat, b2,
                                   u2, c0, Wz_b, bias_z, deg, row_st);
    logits_scatter<<<4096 + 320, 256, 0, stream>>>(x_ln_bf, u2, c0,
                                                   a_src_b, a_dst_b,
                                                   ei, row_st, cnt, csr_src);
    gat_fused<<<N_NODES / 4, 256, 0, stream>>>(x_ln_bf, a_src_b, a_dst_b,
                                               row_st, csr_src, agg_bf);
    gemm_skinny<<<dim3(C_CH / 64, N_NODES / 64), 256, 0, stream>>>(
        agg_bf, Wz_b, bias_z, inp, (float*)d_out, HC);
}

// Round 14
// 185.545 us; speedup vs baseline: 1.2079x; 1.0193x over previous
//
#include <hip/hip_runtime.h>
#include <math.h>

#define N_NODES 16384
#define D_MODEL 256
#define H_HEADS 4
#define C_CH 256
#define E_EDGES 65536
#define ETOT (E_EDGES + N_NODES)
#define HC 1024

typedef __bf16 bf16x8 __attribute__((ext_vector_type(8)));
typedef __bf16 bf16x4 __attribute__((ext_vector_type(4)));
typedef float f32x4 __attribute__((ext_vector_type(4)));

__device__ __forceinline__ __bf16 f2bf(float f) { return (__bf16)f; }
__device__ __forceinline__ float bf2f(__bf16 b) { return (float)b; }

// ==== prep1_ln: 0..63 t-partials | 64..319 compose_v | 320..639 hist |
//                640..4735 LayerNorm (independent of prep outputs) ====
__global__ __launch_bounds__(256) void prep1_ln(
    const float* __restrict__ Wg, const float* __restrict__ att_src,
    const float* __restrict__ att_dst, const float* __restrict__ W2,
    const int* __restrict__ ei, const float* __restrict__ in,
    const float* __restrict__ gamma, const float* __restrict__ beta,
    float* __restrict__ t, float* __restrict__ V, int* __restrict__ deg,
    __bf16* __restrict__ x_ln)
{
    int b = blockIdx.x;
    int tid = threadIdx.x;
    if (b >= 640) {
        int wave = tid >> 6, lane = tid & 63;
        int row = (b - 640) * 4 + wave;
        float4 v = ((const float4*)(in + (size_t)row * D_MODEL))[lane];
        float s  = v.x + v.y + v.z + v.w;
        float sq = v.x*v.x + v.y*v.y + v.z*v.z + v.w*v.w;
        for (int off = 32; off; off >>= 1) {
            s  += __shfl_xor(s,  off);
            sq += __shfl_xor(sq, off);
        }
        float mean = s * (1.0f / D_MODEL);
        float var  = sq * (1.0f / D_MODEL) - mean * mean;
        float inv  = rsqrtf(var + 1e-6f);
        float4 g = ((const float4*)gamma)[lane];
        float4 bb = ((const float4*)beta)[lane];
        bf16x4 o;
        o[0] = f2bf((v.x - mean) * inv * g.x + bb.x);
        o[1] = f2bf((v.y - mean) * inv * g.y + bb.y);
        o[2] = f2bf((v.z - mean) * inv * g.z + bb.z);
        o[3] = f2bf((v.w - mean) * inv * g.w + bb.w);
        *(bf16x4*)(x_ln + (size_t)row * D_MODEL + lane * 4) = o;
        return;
    }
    if (b < 64) {
        int v = b >> 3, sl = b & 7, h = v & 3;
        const float* att = ((v < 4) ? att_src : att_dst) + h * C_CH;
        float acc = 0.f;
        #pragma unroll
        for (int j = 0; j < 32; ++j) {
            int c = sl * 32 + j;
            acc = fmaf(Wg[(size_t)(h * 256 + c) * 256 + tid], att[c], acc);
        }
        atomicAdd(&t[v * 256 + tid], acc);
    } else if (b < 320) {
        int bb = b - 64;
        int og = (bb & 63) * 4, h = bb >> 6;
        const float* w2r = W2 + (size_t)og * 256;
        const float* wgp = Wg + ((size_t)h * 256) * 256 + tid;
        float a0 = 0.f, a1 = 0.f, a2 = 0.f, a3 = 0.f;
        #pragma unroll 4
        for (int c = 0; c < 256; ++c) {
            float wv = wgp[(size_t)c * 256];
            a0 = fmaf(w2r[c],       wv, a0);
            a1 = fmaf(w2r[256 + c], wv, a1);
            a2 = fmaf(w2r[512 + c], wv, a2);
            a3 = fmaf(w2r[768 + c], wv, a3);
        }
        size_t base = (size_t)og * 1024 + h * 256 + tid;
        V[base]        = a0;
        V[base + 1024] = a1;
        V[base + 2048] = a2;
        V[base + 3072] = a3;
    } else {
        int e = (b - 320) * 256 + tid;
        int dst = (e < E_EDGES) ? ei[E_EDGES + e] : (e - E_EDGES);
        atomicAdd(deg + dst, 1);
    }
}

// ==== prep2: blocks 0..63 u2/c0 | 64..319 compose_wz + bias_z | 320 scan ====
__global__ __launch_bounds__(256) void prep2(
    const float* __restrict__ t, const float* __restrict__ W1,
    const float* __restrict__ b1, const float* __restrict__ V,
    const float* __restrict__ W2, const float* __restrict__ bg,
    const float* __restrict__ b2, float* __restrict__ u2,
    float* __restrict__ c0, __bf16* __restrict__ Wz,
    float* __restrict__ bias_z, const int* __restrict__ deg,
    int* __restrict__ row_st)
{
    int b = blockIdx.x;
    int d = threadIdx.x;
    if (b < 64) {
        int v = b >> 3, sl = b & 7;
        const float* tv = t + v * 256;
        float acc = 0.f;
        #pragma unroll
        for (int j = 0; j < 32; ++j) {
            int k = sl * 32 + j;
            acc = fmaf(tv[k], W1[(size_t)k * 256 + d], acc);
        }
        atomicAdd(&u2[v * 256 + d], acc);
        if (d < 32) {
            float p = tv[sl * 32 + d] * b1[sl * 32 + d];
            for (int s = 16; s; s >>= 1) p += __shfl_xor(p, s);
            if (d == 0) atomicAdd(&c0[v], p);
        }
        return;
    }
    if (b == 320) {
        __shared__ int wsum[4];
        int lane = d & 63, wid = d >> 6;
        int base = d * 64;
        int run = 0;
        for (int j = 0; j < 64; ++j) run += deg[base + j];
        int x = run;
        #pragma unroll
        for (int off = 1; off < 64; off <<= 1) {
            int y = __shfl_up(x, off);
            if (lane >= off) x += y;
        }
        if (lane == 63) wsum[wid] = x;
        __syncthreads();
        int woff = 0;
        #pragma unroll
        for (int wdx = 0; wdx < 4; ++wdx)
            if (wdx < wid) woff += wsum[wdx];
        int excl = woff + x - run;
        int run2 = 0;
        for (int j = 0; j < 64; ++j) {
            row_st[base + j] = excl + run2;
            run2 += deg[base + j];
        }
        if (d == 255) row_st[N_NODES] = excl + run2;
        return;
    }
    int bb = b - 64;
    int og = (bb & 63) * 4, h = bb >> 6;
    int lane = d & 63, wid = d >> 6;
    const float* vr = V + (size_t)og * 1024 + h * 256;
    float a0 = 0.f, a1 = 0.f, a2 = 0.f, a3 = 0.f;
    #pragma unroll 4
    for (int k = 0; k < 256; ++k) {
        float w1v = W1[(size_t)k * 256 + d];
        a0 = fmaf(vr[k],        w1v, a0);
        a1 = fmaf(vr[1024 + k], w1v, a1);
        a2 = fmaf(vr[2048 + k], w1v, a2);
        a3 = fmaf(vr[3072 + k], w1v, a3);
    }
    size_t base = (size_t)og * 1024 + h * 256 + d;
    Wz[base]        = f2bf(a0);
    Wz[base + 1024] = f2bf(a1);
    Wz[base + 2048] = f2bf(a2);
    Wz[base + 3072] = f2bf(a3);

    __shared__ float red[4][4];
    float b1v = b1[d];
    #pragma unroll
    for (int j = 0; j < 4; ++j) {
        float p = vr[(size_t)j * 1024 + d] * b1v;
        for (int s = 32; s; s >>= 1) p += __shfl_xor(p, s);
        if (lane == 0) red[j][wid] = p;
    }
    __syncthreads();
    if (d < 4) {
        float s = red[d][0] + red[d][1] + red[d][2] + red[d][3];
        atomicAdd(&bias_z[og + d], 0.25f * s);
    }
    if (h == 0) {
        __syncthreads();
        float bgv = bg[d];
        #pragma unroll
        for (int j = 0; j < 4; ++j) {
            float q = W2[(size_t)(og + j) * 256 + d] * bgv;
            for (int s = 32; s; s >>= 1) q += __shfl_xor(q, s);
            if (lane == 0) red[j][wid] = q;
        }
        __syncthreads();
        if (d < 4) {
            float s = red[d][0] + red[d][1] + red[d][2] + red[d][3];
            atomicAdd(&bias_z[og + d], s + b2[og + d]);
        }
    }
}

// ==== logits_scatter: blocks 0..4095 logits (wave/node) | 4096..4415 scatter ====
__global__ __launch_bounds__(256) void logits_scatter(
    const __bf16* __restrict__ x_ln, const float* __restrict__ u2,
    const float* __restrict__ c0, float* __restrict__ a_src,
    float* __restrict__ a_dst, const int* __restrict__ ei,
    const int* __restrict__ row_st, int* __restrict__ cnt,
    int* __restrict__ csr_src)
{
    int b = blockIdx.x;
    int tid = threadIdx.x;
    if (b >= 4096) {
        int e = (b - 4096) * 256 + tid;
        int src, dst;
        if (e < E_EDGES) { src = ei[e]; dst = ei[E_EDGES + e]; }
        else             { src = dst = e - E_EDGES; }
        int pos = atomicAdd(cnt + dst, 1);
        csr_src[row_st[dst] + pos] = src;
        return;
    }
    __shared__ float u2s[8][256];
    __shared__ float c0s[8];
    #pragma unroll
    for (int k = 0; k < 8; ++k) u2s[k][tid] = u2[k * 256 + tid];
    if (tid < 8) c0s[tid] = c0[tid];
    __syncthreads();

    int wave = tid >> 6, lane = tid & 63;
    int n = b * 4 + wave;
    int v = lane >> 3, p = lane & 7;
    const __bf16* xp = x_ln + (size_t)n * D_MODEL + p * 32;
    const float*  up = &u2s[v][p * 32];
    float acc = 0.f;
    #pragma unroll
    for (int ti = 0; ti < 4; ++ti) {
        bf16x8 x = *(const bf16x8*)(xp + ti * 8);
        #pragma unroll
        for (int j = 0; j < 8; ++j)
            acc = fmaf(bf2f(x[j]), up[ti * 8 + j], acc);
    }
    acc += __shfl_xor(acc, 1);
    acc += __shfl_xor(acc, 2);
    acc += __shfl_xor(acc, 4);
    if (p == 0) {
        float o = acc + c0s[v];
        if (v < 4) a_src[n * H_HEADS + v] = o;
        else       a_dst[n * H_HEADS + (v - 4)] = o;
    }
}

// ---- fused softmax + aggregation, single pass (shift-invariant softmax) ----
__global__ __launch_bounds__(256) void gat_fused(
    const __bf16* __restrict__ x_ln, const float* __restrict__ a_src,
    const float* __restrict__ a_dst, const int* __restrict__ row_start,
    const int* __restrict__ csr_src, __bf16* __restrict__ agg)
{
    int wave = threadIdx.x >> 6, lane = threadIdx.x & 63;
    int i = blockIdx.x * 4 + wave;
    int rs = row_start[i], deg = row_start[i + 1] - rs;
    float4 ad = *(const float4*)(a_dst + i * H_HEADS);

    float acc[4][4] = {};
    float sm0 = 0.f, sm1 = 0.f, sm2 = 0.f, sm3 = 0.f;
    for (int e = 0; e < deg; ++e) {
        int s = csr_src[rs + e];
        float4 as = *(const float4*)(a_src + s * H_HEADS);
        float l0 = as.x + ad.x, l1 = as.y + ad.y, l2 = as.z + ad.z, l3 = as.w + ad.w;
        l0 = (l0 > 0.f) ? l0 : 0.2f * l0;
        l1 = (l1 > 0.f) ? l1 : 0.2f * l1;
        l2 = (l2 > 0.f) ? l2 : 0.2f * l2;
        l3 = (l3 > 0.f) ? l3 : 0.2f * l3;
        float w0 = __expf(l0), w1 = __expf(l1);
        float w2 = __expf(l2), w3 = __expf(l3);
        sm0 += w0; sm1 += w1; sm2 += w2; sm3 += w3;
        bf16x4 x = *(const bf16x4*)(x_ln + (size_t)s * D_MODEL + lane * 4);
        #pragma unroll
        for (int j = 0; j < 4; ++j) {
            float xv = bf2f(x[j]);
            acc[0][j] = fmaf(w0, xv, acc[0][j]);
            acc[1][j] = fmaf(w1, xv, acc[1][j]);
            acc[2][j] = fmaf(w2, xv, acc[2][j]);
            acc[3][j] = fmaf(w3, xv, acc[3][j]);
        }
    }
    float sc[4] = {0.25f / sm0, 0.25f / sm1, 0.25f / sm2, 0.25f / sm3};
    #pragma unroll
    for (int h = 0; h < 4; ++h) {
        bf16x4 o;
        #pragma unroll
        for (int j = 0; j < 4; ++j) o[j] = f2bf(acc[h][j] * sc[h]);
        *(bf16x4*)(agg + (size_t)i * HC + h * 256 + lane * 4) = o;
    }
}

// -------- skinny bf16 GEMM: out[M,256] = A[M,K]·B[256,K]^T + bias + resid --------
// 64x64 tile, BK=128: 8 K-iterations, 16 barriers total (vs 64 at BK=32).
#define GLDP 136   // 272 B row: 16-B aligned; bank aliasing same class as 40

__global__ __launch_bounds__(256) void gemm_skinny(
    const __bf16* __restrict__ A, const __bf16* __restrict__ B,
    const float* __restrict__ bias, const float* __restrict__ resid,
    float* __restrict__ outf, int K)
{
    __shared__ __bf16 As[64 * GLDP];
    __shared__ __bf16 Bs[64 * GLDP];
    int tid  = threadIdx.x;
    int lane = tid & 63;
    int w    = tid >> 6;
    int wm   = w >> 1, wn = w & 1;
    int quad = lane >> 4;
    int l16  = lane & 15;
    int m0 = blockIdx.y * 64;
    int n0 = blockIdx.x * 64;

    f32x4 acc[2][2] = {};

    for (int kb = 0; kb < K; kb += 128) {
        // stage 64x128 A and B tiles: 1024 16B-chunks each, 4 per thread
        bf16x8 areg[4], breg[4];
        #pragma unroll
        for (int t = 0; t < 4; ++t) {
            int c = tid + t * 256;
            int r = c >> 4, p = c & 15;
            areg[t] = *(const bf16x8*)(A + (size_t)(m0 + r) * K + kb + p * 8);
            breg[t] = *(const bf16x8*)(B + (size_t)(n0 + r) * K + kb + p * 8);
        }
        __syncthreads();   // previous iteration's LDS reads complete
        #pragma unroll
        for (int t = 0; t < 4; ++t) {
            int c = tid + t * 256;
            int r = c >> 4, p = c & 15;
            *(bf16x8*)(As + r * GLDP + p * 8) = areg[t];
            *(bf16x8*)(Bs + r * GLDP + p * 8) = breg[t];
        }
        __syncthreads();
        #pragma unroll
        for (int ks = 0; ks < 4; ++ks) {
            bf16x8 af[2], bfr[2];
            #pragma unroll
            for (int mt = 0; mt < 2; ++mt)
                af[mt] = *(const bf16x8*)(As + (wm * 32 + mt * 16 + l16) * GLDP
                                          + ks * 32 + quad * 8);
            #pragma unroll
            for (int nt = 0; nt < 2; ++nt)
                bfr[nt] = *(const bf16x8*)(Bs + (wn * 32 + nt * 16 + l16) * GLDP
                                           + ks * 32 + quad * 8);
            #pragma unroll
            for (int mt = 0; mt < 2; ++mt)
                #pragma unroll
                for (int nt = 0; nt < 2; ++nt)
                    acc[mt][nt] = __builtin_amdgcn_mfma_f32_16x16x32_bf16(
                        af[mt], bfr[nt], acc[mt][nt], 0, 0, 0);
        }
    }

    int rowb = m0 + wm * 32;
    int colb = n0 + wn * 32;
    #pragma unroll
    for (int nt = 0; nt < 2; ++nt) {
        int col = colb + nt * 16 + l16;
        float bv = bias[col];
        #pragma unroll
        for (int mt = 0; mt < 2; ++mt) {
            int row = rowb + mt * 16 + quad * 4;
            #pragma unroll
            for (int r = 0; r < 4; ++r) {
                size_t off = (size_t)(row + r) * C_CH + col;
                outf[off] = acc[mt][nt][r] + bv + resid[off];
            }
        }
    }
}

extern "C" void kernel_launch(void* const* d_in, const int* in_sizes, int n_in,
                              void* d_out, int out_size, void* d_ws, size_t ws_size,
                              hipStream_t stream)
{
    const float* inp      = (const float*)d_in[0];
    const int*   ei       = (const int*)  d_in[1];
    const float* ln_gamma = (const float*)d_in[2];
    const float* ln_beta  = (const float*)d_in[3];
    const float* W1       = (const float*)d_in[4];
    const float* b1       = (const float*)d_in[5];
    const float* W_gat    = (const float*)d_in[6];
    const float* att_src  = (const float*)d_in[7];
    const float* att_dst  = (const float*)d_in[8];
    const float* bias_gat = (const float*)d_in[9];
    const float* W2       = (const float*)d_in[10];
    const float* b2       = (const float*)d_in[11];

    char* ws = (char*)d_ws;
    __bf16* x_ln_bf   = (__bf16*)(ws);                        //  8 MB
    __bf16* agg_bf    = (__bf16*)(ws + (8ull  << 20));        // 32 MB
    float*  V_f       = (float*)(ws + (40ull << 20));         //  1 MB
    __bf16* Wz_b      = (__bf16*)(ws + (41ull << 20));        // 512 KB
    float*  a_src_b   = (float*)(ws + (42ull << 20));         // 256 KB
    float*  a_dst_b   = a_src_b + (size_t)N_NODES * H_HEADS;  // 256 KB
    // ---- zero region start ----
    float*  t_vec     = a_dst_b + (size_t)N_NODES * H_HEADS;  //  8 KB
    float*  u2        = t_vec + 8 * 256;                      //  8 KB
    float*  c0        = u2 + 8 * 256;                         //  32 B
    float*  bias_z    = c0 + 8;                               //  1 KB
    int*    deg       = (int*)(bias_z + 256);                 // 64 KB
    int*    cnt       = deg + N_NODES;                        // 64 KB
    // ---- zero region end ----
    int*    row_st    = cnt + N_NODES;
    int*    csr_src   = row_st + N_NODES + 4;

    size_t zbytes = (8 * 256 + 8 * 256 + 8 + 256) * sizeof(float)
                  + 2 * N_NODES * sizeof(int);
    hipMemsetAsync(t_vec, 0, zbytes, stream);

    // prep1 + LayerNorm overlapped; prep2 + scan; logits + scatter
    prep1_ln<<<640 + 4096, 256, 0, stream>>>(W_gat, att_src, att_dst, W2, ei,
                                             inp, ln_gamma, ln_beta,
                                             t_vec, V_f, deg, x_ln_bf);
    prep2<<<321, 256, 0, stream>>>(t_vec, W1, b1, V_f, W2, bias_gat, b2,
                                   u2, c0, Wz_b, bias_z, deg, row_st);
    logits_scatter<<<4096 + 320, 256, 0, stream>>>(x_ln_bf, u2, c0,
                                                   a_src_b, a_dst_b,
                                                   ei, row_st, cnt, csr_src);
    gat_fused<<<N_NODES / 4, 256, 0, stream>>>(x_ln_bf, a_src_b, a_dst_b,
                                               row_st, csr_src, agg_bf);
    gemm_skinny<<<dim3(C_CH / 64, N_NODES / 64), 256, 0, stream>>>(
        agg_bf, Wz_b, bias_z, inp, (float*)d_out, HC);
}